// Round 9
// baseline (351.931 us; speedup 1.0000x reference)
//
#include <hip/hip_runtime.h>
#include <hip/hip_bf16.h>

#define NN 4096
#define DD 256
#define BB 32
#define TT 256
#define EPS 1e-6f
#define DECAY 0.97f
#define LOG2_DECAY -0.043943348f

typedef __hip_bfloat16 bf16;
typedef short short8 __attribute__((ext_vector_type(8)));
typedef float floatx4 __attribute__((ext_vector_type(4)));

__device__ __forceinline__ float bfu2f(short u) {
    return __uint_as_float(((unsigned)(unsigned short)u) << 16);
}

__device__ __forceinline__ short f2bfu(float f) {
    bf16 t = __float2bfloat16(f);
    return *reinterpret_cast<short*>(&t);
}

// ---------------- block-wide sum over 256 threads ----------------
__device__ __forceinline__ float blk_sum_256(float v, volatile float* s4) {
#pragma unroll
    for (int o = 32; o > 0; o >>= 1) v += __shfl_down(v, o, 64);
    int lane = threadIdx.x & 63, w = threadIdx.x >> 6;
    __syncthreads();
    if (lane == 0) s4[w] = v;
    __syncthreads();
    return s4[0] + s4[1] + s4[2] + s4[3];
}

// async global->LDS, 16B per lane; LDS dest must be wave-uniform base + lane*16
__device__ __forceinline__ void gl16(const bf16* g, bf16* l) {
    __builtin_amdgcn_global_load_lds((const __attribute__((address_space(1))) void*)g,
                                     (__attribute__((address_space(3))) void*)l, 16, 0, 0);
}

// ---------------- dtype detector (bf16-packed vs fp32 inputs) ----------------
__global__ void k_detect(const unsigned short* __restrict__ raw, int* __restrict__ flag) {
    __shared__ int cnt[4];
    int tid = threadIdx.x;
    int bad = 0;
    for (int i = tid; i < 8192; i += 256) {
        unsigned int u = raw[2 * i];
        float v = __uint_as_float(u << 16);
        if (!(fabsf(v) < 1e6f)) bad++;
    }
#pragma unroll
    for (int o = 32; o > 0; o >>= 1) bad += __shfl_down(bad, o, 64);
    int lane = tid & 63, w = tid >> 6;
    if (lane == 0) cnt[w] = bad;
    __syncthreads();
    if (tid == 0) flag[0] = (cnt[0] + cnt[1] + cnt[2] + cnt[3] < 32) ? 1 : 0;
}

// ---------------- convert 3 weight matrices to bf16, 8 elems/thread ----------------
__global__ __launch_bounds__(256) void k_convert3(const void* __restrict__ s0,
                                                  const void* __restrict__ s1,
                                                  const void* __restrict__ s2,
                                                  bf16* __restrict__ d0,
                                                  bf16* __restrict__ d1,
                                                  bf16* __restrict__ d2,
                                                  const int* __restrict__ flag) {
    const int per = NN * DD / 8;  // 131072 16B-chunks per matrix
    int i = blockIdx.x * 256 + threadIdx.x;
    int m = i / per, j = i % per;
    const void* s = (m == 0) ? s0 : (m == 1) ? s1 : s2;
    bf16* d = (m == 0) ? d0 : (m == 1) ? d1 : d2;
    if (flag[0]) {
        ((uint4*)d)[j] = ((const uint4*)s)[j];  // already bf16: straight copy
    } else {
        const float4* f = (const float4*)s;
        float4 a = f[2 * j], b = f[2 * j + 1];
        short8 o;
        float va[8] = {a.x, a.y, a.z, a.w, b.x, b.y, b.z, b.w};
#pragma unroll
        for (int k = 0; k < 8; k++) o[k] = f2bfu(va[k]);
        ((short8*)d)[j] = o;
    }
}

// ---------------- gather embeddings: Vp (raw) and U=LN(row), both bf16 ----------------
__global__ __launch_bounds__(256) void k_gather_ln(const void* __restrict__ emb,
                                                   const int* __restrict__ idx,
                                                   bf16* __restrict__ Vpb,
                                                   bf16* __restrict__ Ub,
                                                   const int* __restrict__ flag) {
    __shared__ float s4[4];
    int r = blockIdx.x, d = threadIdx.x;
    int tok = idx[r];
    long o = (long)tok * DD + d;
    float e = flag[0] ? __bfloat162float(((const bf16*)emb)[o]) : ((const float*)emb)[o];
    Vpb[(long)r * DD + d] = __float2bfloat16(e);
    float m = blk_sum_256(e, s4) * (1.0f / DD);
    float zc = e - m;
    float var = blk_sum_256(zc * zc, s4) * (1.0f / (DD - 1));
    Ub[(long)r * DD + d] = __float2bfloat16(zc / (sqrtf(fmaxf(var, 0.f)) + EPS));
}

// ---------------- per-batch transpose Ub[b][t][d] -> Ut[b][d][t] ----------------
__global__ __launch_bounds__(256) void k_transpose(const bf16* __restrict__ Ub,
                                                   bf16* __restrict__ Ut) {
    __shared__ bf16 tile[32][33];
    int b = blockIdx.z;
    int t0 = blockIdx.x * 32, d0 = blockIdx.y * 32;
    const bf16* src = Ub + (long)b * TT * DD;
    bf16* dst = Ut + (long)b * DD * TT;
    int rr = threadIdx.x >> 3, c4 = (threadIdx.x & 7) * 4;
#pragma unroll
    for (int i = 0; i < 4; i++) tile[rr][c4 + i] = src[(long)(t0 + rr) * DD + d0 + c4 + i];
    __syncthreads();
#pragma unroll
    for (int i = 0; i < 4; i++) dst[(long)(d0 + rr) * TT + t0 + c4 + i] = tile[c4 + i][rr];
}

enum { EPI_RELU_BF16 = 0, EPI_NONE_F32 = 1, EPI_RELU_MULX_BF16 = 2, EPI_NONE_BF16 = 3,
       EPI_MASK_BF16 = 4 };

// ---------------- 256x256-tile K=256 GEMM for W/Y (round-4 v1, best measured) ----------------
template <int EPI>
__global__ __launch_bounds__(512, 2) void k_fused256(const bf16* __restrict__ A,  // M x 256
                                                     const bf16* __restrict__ B,  // N x 256
                                                     bf16* __restrict__ C,        // M x NN
                                                     const bf16* __restrict__ Xaux,
                                                     float* __restrict__ Wsum) {
    __shared__ __align__(16) char smem[65536];  // 2 x (As 16KB | Bs 16KB); epi overlay 33.8KB
    bf16* R = (bf16*)smem;                      // [64][264] repack overlay (post-loop)

    int bx = blockIdx.x, by = blockIdx.y;
    {   // bijective XCD swizzle (nwg = 512, %8 == 0)
        int gx = gridDim.x;
        int nwg = gx * gridDim.y;
        int id = by * gx + bx;
        int q = nwg >> 3;
        int nid = (id & 7) * q + (id >> 3);
        bx = nid % gx;
        by = nid / gx;
    }
    int bm = by * 256, bn = bx * 256;
    int tid = threadIdx.x, wid = tid >> 6, lane = tid & 63;
    int wr = wid >> 2, wc = wid & 3;       // wave grid 2(M) x 4(N); wave tile 128x64
    int lm = lane & 15, kh = lane >> 4;

    int srow2 = tid >> 2;
    int swzcol = (((tid & 3) ^ ((srow2 >> 1) & 3)) << 3);
    const bf16* gA0 = A + (long)(bm + srow2) * DD + swzcol;
    const bf16* gA1 = gA0 + (long)128 * DD;
    const bf16* gB0 = B + (long)(bn + srow2) * DD + swzcol;
    const bf16* gB1 = gB0 + (long)128 * DD;
    int chunk = ((kh ^ ((lm >> 1) & 3)) << 3);

    floatx4 acc[8][4];
#pragma unroll
    for (int i = 0; i < 8; i++)
#pragma unroll
        for (int j = 0; j < 4; j++) acc[i][j] = (floatx4){0.f, 0.f, 0.f, 0.f};

#define STAGE256(SBASE, KK)                             \
    {                                                   \
        bf16* As_ = (bf16*)(SBASE);                     \
        bf16* Bs_ = As_ + 8192;                         \
        gl16(gA0 + (KK), As_ + tid * 8);                \
        gl16(gA1 + (KK), As_ + 4096 + tid * 8);         \
        gl16(gB0 + (KK), Bs_ + tid * 8);                \
        gl16(gB1 + (KK), Bs_ + 4096 + tid * 8);         \
    }

    STAGE256(smem, 0);  // prologue: stage k-step 0 into buffer 0

    int cur = 0;
#pragma unroll
    for (int k0 = 0; k0 < 256; k0 += 32) {
        __builtin_amdgcn_s_barrier();  // prev compute done -> other buffer free
        __builtin_amdgcn_sched_barrier(0);
        if (k0 + 32 < 256) STAGE256(smem + ((cur ^ 1) * 32768), k0 + 32);
        if (k0 + 32 < 256) asm volatile("s_waitcnt vmcnt(4)" ::: "memory");  // stage t landed
        else               asm volatile("s_waitcnt vmcnt(0)" ::: "memory");
        __builtin_amdgcn_s_barrier();  // all waves' stage-t writes visible
        __builtin_amdgcn_sched_barrier(0);
        bf16* cbA = (bf16*)(smem + cur * 32768);
        bf16* cbB = cbA + 8192;
        short8 af[8], bfr[4];
#pragma unroll
        for (int i = 0; i < 8; i++)
            af[i] = *(const short8*)(cbA + (wr * 128 + i * 16 + lm) * 32 + chunk);
#pragma unroll
        for (int j = 0; j < 4; j++)
            bfr[j] = *(const short8*)(cbB + (wc * 64 + j * 16 + lm) * 32 + chunk);
#pragma unroll
        for (int i = 0; i < 8; i++)
#pragma unroll
            for (int j = 0; j < 4; j++)
                acc[i][j] = __builtin_amdgcn_mfma_f32_16x16x32_bf16(af[i], bfr[j], acc[i][j], 0, 0, 0);
        cur ^= 1;
    }
#undef STAGE256

    // ---- LDS-repack epilogue: four 64-row passes, coalesced 16B stores ----
#pragma unroll
    for (int p = 0; p < 4; p++) {
        __syncthreads();
        if (wr == (p >> 1)) {
            int ibase = (p & 1) * 4;
#pragma unroll
            for (int ii = 0; ii < 4; ii++)
#pragma unroll
                for (int j = 0; j < 4; j++)
#pragma unroll
                    for (int r = 0; r < 4; r++) {
                        int rr = ii * 16 + kh * 4 + r;
                        int cc = wc * 64 + j * 16 + lm;
                        R[rr * 264 + cc] = __float2bfloat16(fmaxf(acc[ibase + ii][j][r], 0.f));
                    }
        }
        __syncthreads();
#pragma unroll
        for (int it = 0; it < 4; it++) {
            int row_l = it * 16 + (tid >> 5);
            int c8 = (tid & 31) * 8;
            short8 vv = *(const short8*)(R + row_l * 264 + c8);
            int gm = bm + p * 64 + row_l;
            long off = (long)gm * NN + bn + c8;
            if (EPI == EPI_RELU_BF16) {
                *(short8*)(C + off) = vv;
                float s = 0.f;
#pragma unroll
                for (int k = 0; k < 8; k++) s += bfu2f(vv[k]);
#pragma unroll
                for (int o = 16; o > 0; o >>= 1) s += __shfl_down(s, o, 32);
                if ((tid & 31) == 0) atomicAdd(&Wsum[gm], s);
            } else {  // EPI_RELU_MULX_BF16
                short8 xx = *(const short8*)(Xaux + off);
                short8 oo;
#pragma unroll
                for (int k = 0; k < 8; k++) {
                    float prod = bfu2f(vv[k]) * fmaxf(bfu2f(xx[k]), 0.f);
                    oo[k] = f2bfu(prod);
                }
                *(short8*)(C + off) = oo;
            }
        }
    }
}

// ---------------- MFMA bf16 NT GEMM (long-K path): triple-buffered counted ----------------
template <int EPI, int KSPLIT, int TRI, int SWZ>
__global__ __launch_bounds__(256) void k_mfma_nt(int K,
                                                 const bf16* __restrict__ A, int lda, long sA,
                                                 const bf16* __restrict__ B, int ldb, long sB,
                                                 void* __restrict__ Cv, int ldc, long sC,
                                                 const bf16* __restrict__ Xaux,
                                                 float* __restrict__ Wsum) {
    __shared__ __align__(16) char smem[49152];  // 3 x (As 8KB | Bs 8KB)
    bf16* R = (bf16*)smem;  // [64][136] repack buffer (overlays buffers, used post-loop)

    int z = blockIdx.z;
    int bz = z / KSPLIT, ks = z % KSPLIT;
    A += (long)bz * sA;
    B += (long)bz * sB;
    int bx = blockIdx.x, by = blockIdx.y;
    if (TRI) {  // 3-tile lower-triangular mapping: 0->(0,0) 1->(1,0) 2->(1,1)
        by = (blockIdx.x >= 1) ? 1 : 0;
        bx = (blockIdx.x == 2) ? 1 : 0;
    }
    if (SWZ) {  // bijective XCD swizzle over the xy-plane (requires nwg%8==0)
        int gx = gridDim.x;
        int nwg = gx * gridDim.y;
        int id = by * gx + bx;
        int q = nwg >> 3;
        int nid = (id & 7) * q + (id >> 3);
        bx = nid % gx;
        by = nid / gx;
    }
    int bm = by * 128, bn = bx * 128;
    int tid = threadIdx.x;
    int srow = tid >> 2;
    int scol = ((((srow >> 1) & 3) ^ (tid & 3)) << 3);
    int w = tid >> 6, lane = tid & 63;
    int wm = (w >> 1) * 64, wn = (w & 1) * 64;
    int lm = lane & 15, kh = lane >> 4;

    floatx4 acc[4][4];
#pragma unroll
    for (int i = 0; i < 4; i++)
#pragma unroll
        for (int j = 0; j < 4; j++) acc[i][j] = (floatx4){0.f, 0.f, 0.f, 0.f};

    int kchunk = K / KSPLIT;
    int kbeg = ks * kchunk, kend = kbeg + kchunk;
    const bf16* gA0 = A + (long)(bm + srow) * lda + scol;
    const bf16* gA1 = gA0 + (long)64 * lda;
    const bf16* gB0 = B + (long)(bn + srow) * ldb + scol;
    const bf16* gB1 = gB0 + (long)64 * ldb;
    int dslot = tid * 8;  // bf16 elements

#define STAGE_SLOT(SBASE, KK)                          \
    {                                                  \
        bf16* bufA = (bf16*)(SBASE);                   \
        bf16* bufB = bufA + 4096;                      \
        gl16(gA0 + (KK), bufA + dslot);                \
        gl16(gA1 + (KK), bufA + 2048 + dslot);         \
        gl16(gB0 + (KK), bufB + dslot);                \
        gl16(gB1 + (KK), bufB + 2048 + dslot);         \
    }

    // prologue: prefetch distance 2
    STAGE_SLOT(smem, kbeg);
    if (kbeg + 32 < kend) STAGE_SLOT(smem + 16384, kbeg + 32);

    int cur = 0;
    for (int k0 = kbeg; k0 < kend; k0 += 32) {
        __builtin_amdgcn_s_barrier();
        __builtin_amdgcn_sched_barrier(0);
        if (k0 + 64 < kend) {
            int ps = (cur == 0) ? 2 : cur - 1;  // (cur+2)%3
            STAGE_SLOT(smem + ps * 16384, k0 + 64);
        }
        int rem = (kend - k0 - 32) >> 5;
        if (rem >= 2)      asm volatile("s_waitcnt vmcnt(8)" ::: "memory");
        else if (rem == 1) asm volatile("s_waitcnt vmcnt(4)" ::: "memory");
        else               asm volatile("s_waitcnt vmcnt(0)" ::: "memory");
        __builtin_amdgcn_s_barrier();
        __builtin_amdgcn_sched_barrier(0);
        bf16* cbA = (bf16*)(smem + cur * 16384);
        bf16* cbB = cbA + 4096;
        short8 af[4], bfr[4];
#pragma unroll
        for (int i = 0; i < 4; i++) {
            int row = wm + i * 16 + lm;
            af[i] = *(const short8*)(cbA + row * 32 + ((((row >> 1) & 3) ^ kh) << 3));
        }
#pragma unroll
        for (int j = 0; j < 4; j++) {
            int row = wn + j * 16 + lm;
            bfr[j] = *(const short8*)(cbB + row * 32 + ((((row >> 1) & 3) ^ kh) << 3));
        }
#pragma unroll
        for (int i = 0; i < 4; i++)
#pragma unroll
            for (int j = 0; j < 4; j++)
                acc[i][j] = __builtin_amdgcn_mfma_f32_16x16x32_bf16(af[i], bfr[j], acc[i][j], 0, 0, 0);
        cur = (cur == 2) ? 0 : cur + 1;
    }
#undef STAGE_SLOT

    if (EPI == EPI_NONE_F32) {
        long cbase = (long)z * sC;
#pragma unroll
        for (int i = 0; i < 4; i++)
#pragma unroll
            for (int j = 0; j < 4; j++)
#pragma unroll
                for (int r = 0; r < 4; r++) {
                    int gm = bm + wm + i * 16 + kh * 4 + r;
                    int gn = bn + wn + j * 16 + lm;
                    ((float*)Cv)[cbase + (long)gm * ldc + gn] = acc[i][j][r];
                }
        return;
    }

    // ---- LDS-repack epilogue: two 64-row passes, coalesced 16B stores ----
    bf16* Cb = (bf16*)Cv + (long)z * sC;
#pragma unroll
    for (int p = 0; p < 2; p++) {
        __syncthreads();
        if ((w >> 1) == p) {
#pragma unroll
            for (int i = 0; i < 4; i++)
#pragma unroll
                for (int j = 0; j < 4; j++)
#pragma unroll
                    for (int r = 0; r < 4; r++) {
                        int rr = i * 16 + kh * 4 + r;
                        int cc = wn + j * 16 + lm;
                        float val = acc[i][j][r];
                        if (EPI == EPI_RELU_BF16 || EPI == EPI_RELU_MULX_BF16) val = fmaxf(val, 0.f);
                        R[rr * 136 + cc] = __float2bfloat16(val);
                    }
        }
        __syncthreads();
#pragma unroll
        for (int it = 0; it < 4; it++) {
            int row_l = it * 16 + (tid >> 4);
            int c8 = (tid & 15) * 8;
            short8 vv = *(const short8*)(R + row_l * 136 + c8);
            int gm = bm + p * 64 + row_l;
            long off = (long)gm * ldc + bn + c8;
            if (EPI == EPI_NONE_BF16) {
                *(short8*)(Cb + off) = vv;
            } else if (EPI == EPI_MASK_BF16) {
                short8 oo;
#pragma unroll
                for (int k = 0; k < 8; k++) {
                    int s = bn + c8 + k;
                    float f = bfu2f(vv[k]);
                    f = (s < gm) ? f * exp2f((float)(gm - s) * LOG2_DECAY) : 0.f;
                    oo[k] = f2bfu(f);
                }
                *(short8*)(Cb + off) = oo;
            } else if (EPI == EPI_RELU_BF16) {
                *(short8*)(Cb + off) = vv;
                float s = 0.f;
#pragma unroll
                for (int k = 0; k < 8; k++) s += bfu2f(vv[k]);
#pragma unroll
                for (int o = 8; o > 0; o >>= 1) s += __shfl_down(s, o, 16);
                if ((tid & 15) == 0) atomicAdd(&Wsum[gm], s);
            } else {  // EPI_RELU_MULX_BF16
                short8 xx = *(const short8*)(Xaux + off);
                short8 oo;
#pragma unroll
                for (int k = 0; k < 8; k++) {
                    float prod = bfu2f(vv[k]) * fmaxf(bfu2f(xx[k]), 0.f);
                    oo[k] = f2bfu(prod);
                }
                *(short8*)(Cb + off) = oo;
            }
        }
    }
}

// ---------------- Z GEMM: BM=128, BN=256(=DD full), split-K 4, bf16 partials ----------------
// Reads Xb ONCE (vs 2x with 128-col blocks). 8 waves, wave-tile 64x64,
// double-buffered counted-vmcnt schedule + 0-conflict chunk-XOR swizzle
// (both proven in k_fused256). Coalesced bf16 repack epilogue.
__global__ __launch_bounds__(512, 2) void k_zgemm(const bf16* __restrict__ A,   // M x NN (Xb)
                                                  const bf16* __restrict__ B,   // DD x NN (Eb)
                                                  bf16* __restrict__ Zp) {      // 4 x M x DD
    __shared__ __align__(16) char smem[49152];  // 2 x (As 8KB | Bs 16KB)
    bf16* R = (bf16*)smem;                      // [64][264] repack overlay

    int bx = blockIdx.x;  // 64 M-tiles
    {   // bijective XCD swizzle (64 % 8 == 0)
        int nid = (bx & 7) * 8 + (bx >> 3);
        bx = nid;
    }
    int ks = blockIdx.y;  // 4 K-splits
    int bm = bx * 128;
    int kbeg = ks * 1024, kend = kbeg + 1024;

    int tid = threadIdx.x, wid = tid >> 6, lane = tid & 63;
    int wr = wid >> 2, wc = wid & 3;  // wave grid 2(M) x 4(N); wave tile 64x64
    int lm = lane & 15, kh = lane >> 4;

    int srow = tid >> 2;  // 0..127
    int swzcol = (((tid & 3) ^ ((srow >> 1) & 3)) << 3);
    const bf16* gA  = A + (long)(bm + srow) * NN + swzcol;
    const bf16* gB0 = B + (long)srow * NN + swzcol;          // Eb rows 0-127
    const bf16* gB1 = gB0 + (long)128 * NN;                  // Eb rows 128-255
    int chunk = ((kh ^ ((lm >> 1) & 3)) << 3);

    floatx4 acc[4][4];
#pragma unroll
    for (int i = 0; i < 4; i++)
#pragma unroll
        for (int j = 0; j < 4; j++) acc[i][j] = (floatx4){0.f, 0.f, 0.f, 0.f};

#define STAGEZ(SBASE, KK)                               \
    {                                                   \
        bf16* As_ = (bf16*)(SBASE);                     \
        bf16* Bs_ = As_ + 4096;                         \
        gl16(gA + (KK), As_ + tid * 8);                 \
        gl16(gB0 + (KK), Bs_ + tid * 8);                \
        gl16(gB1 + (KK), Bs_ + 4096 + tid * 8);         \
    }

    STAGEZ(smem, kbeg);  // prologue

    int cur = 0;
    for (int k0 = kbeg; k0 < kend; k0 += 32) {
        __builtin_amdgcn_s_barrier();
        __builtin_amdgcn_sched_barrier(0);
        bool has = (k0 + 32) < kend;
        if (has) STAGEZ(smem + ((cur ^ 1) * 24576), k0 + 32);
        if (has) asm volatile("s_waitcnt vmcnt(3)" ::: "memory");
        else     asm volatile("s_waitcnt vmcnt(0)" ::: "memory");
        __builtin_amdgcn_s_barrier();
        __builtin_amdgcn_sched_barrier(0);
        bf16* cbA = (bf16*)(smem + cur * 24576);
        bf16* cbB = cbA + 4096;
        short8 af[4], bfr[4];
#pragma unroll
        for (int i = 0; i < 4; i++)
            af[i] = *(const short8*)(cbA + (wr * 64 + i * 16 + lm) * 32 + chunk);
#pragma unroll
        for (int j = 0; j < 4; j++)
            bfr[j] = *(const short8*)(cbB + (wc * 64 + j * 16 + lm) * 32 + chunk);
#pragma unroll
        for (int i = 0; i < 4; i++)
#pragma unroll
            for (int j = 0; j < 4; j++)
                acc[i][j] = __builtin_amdgcn_mfma_f32_16x16x32_bf16(af[i], bfr[j], acc[i][j], 0, 0, 0);
        cur ^= 1;
    }
#undef STAGEZ

    // ---- repack epilogue: two 64-row passes, coalesced 16B stores ----
    bf16* Cb = Zp + (long)ks * 8192 * DD;
#pragma unroll
    for (int p = 0; p < 2; p++) {
        __syncthreads();
        if (wr == p) {
#pragma unroll
            for (int i = 0; i < 4; i++)
#pragma unroll
                for (int j = 0; j < 4; j++)
#pragma unroll
                    for (int r = 0; r < 4; r++) {
                        int rr = i * 16 + kh * 4 + r;
                        int cc = wc * 64 + j * 16 + lm;
                        R[rr * 264 + cc] = __float2bfloat16(acc[i][j][r]);
                    }
        }
        __syncthreads();
#pragma unroll
        for (int it = 0; it < 4; it++) {
            int row_l = it * 16 + (tid >> 5);
            int c8 = (tid & 31) * 8;
            short8 vv = *(const short8*)(R + row_l * 264 + c8);
            int gm = bm + p * 64 + row_l;
            *(short8*)(Cb + (long)gm * DD + c8) = vv;
        }
    }
}

// ---------------- a* GEMM (unchanged from R8) ----------------
__global__ __launch_bounds__(256) void k_astar(const bf16* __restrict__ Gp,
                                               const bf16* __restrict__ Ut,
                                               bf16* __restrict__ Ap) {
    __shared__ __align__(16) char smem[32768];
    bf16* R = (bf16*)smem;

    int b = blockIdx.z;
    int y = blockIdx.y;
    int by = (y >= 1) ? 1 : 0, ks = (y == 2) ? 1 : 0;
    int bx = blockIdx.x;
    int bm = by * 128, bn = bx * 128, kbeg = ks * 128;
    int tid = threadIdx.x;
    int srow = tid >> 2;
    int scol = ((((srow >> 1) & 3) ^ (tid & 3)) << 3);
    int w = tid >> 6, lane = tid & 63;
    int wm = (w >> 1) * 64, wn = (w & 1) * 64;
    int lm = lane & 15, kh = lane >> 4;

    const bf16* gA = Gp + (long)b * 4 * 65536;
    long aoff0 = (long)(bm + srow) * TT + scol + kbeg;
    long aoff1 = (long)(bm + srow + 64) * TT + scol + kbeg;
    const bf16* gB0 = Ut + (long)b * DD * TT + (long)(bn + srow) * TT + scol + kbeg;
    const bf16* gB1 = gB0 + (long)64 * TT;
    int dslot = tid * 8;

    floatx4 acc[4][4];
#pragma unroll
    for (int i = 0; i < 4; i++)
#pragma unroll
        for (int j = 0; j < 4; j++) acc[i][j] = (floatx4){0.f, 0.f, 0.f, 0.f};

#define LOAD4SUM(DST, AOFF)                                        \
    {                                                              \
        short8 p0 = *(const short8*)(gA + (AOFF));                 \
        short8 p1 = *(const short8*)(gA + 65536 + (AOFF));         \
        short8 p2 = *(const short8*)(gA + 2 * 65536 + (AOFF));     \
        short8 p3 = *(const short8*)(gA + 3 * 65536 + (AOFF));     \
        short8 o_;                                                 \
        _Pragma("unroll")                                          \
        for (int k_ = 0; k_ < 8; k_++)                             \
            o_[k_] = f2bfu(bfu2f(p0[k_]) + bfu2f(p1[k_]) +         \
                           bfu2f(p2[k_]) + bfu2f(p3[k_]));         \
        DST = o_;                                                  \
    }

    {
        bf16* As_ = (bf16*)smem;
        bf16* Bs_ = As_ + 4096;
        gl16(gB0, Bs_ + dslot);
        gl16(gB1, Bs_ + 2048 + dslot);
        short8 ra0, ra1;
        LOAD4SUM(ra0, aoff0);
        LOAD4SUM(ra1, aoff1);
        *(short8*)(As_ + dslot) = ra0;
        *(short8*)(As_ + 2048 + dslot) = ra1;
    }
    __syncthreads();

    int cur = 0;
    for (int kk = 0; kk < 128; kk += 32) {
        bf16* cbA = (bf16*)(smem + cur * 16384);
        bf16* cbB = cbA + 4096;
        bf16* nbA = (bf16*)(smem + (cur ^ 1) * 16384);
        bf16* nbB = nbA + 4096;
        short8 na0, na1;
        bool has = (kk + 32) < 128;
        if (has) {
            gl16(gB0 + kk + 32, nbB + dslot);
            gl16(gB1 + kk + 32, nbB + 2048 + dslot);
            LOAD4SUM(na0, aoff0 + kk + 32);
            LOAD4SUM(na1, aoff1 + kk + 32);
        }
        short8 af[4], bfr[4];
#pragma unroll
        for (int i = 0; i < 4; i++) {
            int row = wm + i * 16 + lm;
            af[i] = *(const short8*)(cbA + row * 32 + ((((row >> 1) & 3) ^ kh) << 3));
        }
#pragma unroll
        for (int j = 0; j < 4; j++) {
            int row = wn + j * 16 + lm;
            bfr[j] = *(const short8*)(cbB + row * 32 + ((((row >> 1) & 3) ^ kh) << 3));
        }
#pragma unroll
        for (int i = 0; i < 4; i++)
#pragma unroll
            for (int j = 0; j < 4; j++)
                acc[i][j] = __builtin_amdgcn_mfma_f32_16x16x32_bf16(af[i], bfr[j], acc[i][j], 0, 0, 0);
        if (has) {
            *(short8*)(nbA + dslot) = na0;
            *(short8*)(nbA + 2048 + dslot) = na1;
        }
        __syncthreads();
        cur ^= 1;
    }
#undef LOAD4SUM

    bf16* Cb = Ap + ((long)b * 2 + ks) * 65536;
#pragma unroll
    for (int p = 0; p < 2; p++) {
        __syncthreads();
        if ((w >> 1) == p) {
#pragma unroll
            for (int i = 0; i < 4; i++)
#pragma unroll
                for (int j = 0; j < 4; j++)
#pragma unroll
                    for (int r = 0; r < 4; r++) {
                        int rr = i * 16 + kh * 4 + r;
                        int cc = wn + j * 16 + lm;
                        R[rr * 136 + cc] = __float2bfloat16(acc[i][j][r]);
                    }
        }
        __syncthreads();
#pragma unroll
        for (int it = 0; it < 4; it++) {
            int row_l = it * 16 + (tid >> 4);
            int c8 = (tid & 15) * 8;
            short8 vv = *(const short8*)(R + row_l * 136 + c8);
            int gm = bm + p * 64 + row_l;
            *(short8*)(Cb + (long)gm * DD + bn + c8) = vv;
        }
    }
}

// ---------------- scalar normalizer recurrence ----------------
__global__ __launch_bounds__(256) void k_scalar_scan(const float* __restrict__ Wsum,
                                                     float* __restrict__ invS) {
    __shared__ float sw[BB * TT];
    for (int i = threadIdx.x; i < BB * TT; i += 256) sw[i] = Wsum[i];
    __syncthreads();
    int b = threadIdx.x;
    if (b < BB) {
        float sig = 0.f;
        for (int t = 0; t < TT; t++) {
            float S = DECAY * sig + sw[b * TT + t];
            float inv = 1.f / (S + EPS);
            invS[b * TT + t] = inv;
            sig = S * inv;
        }
    }
}

// ---------------- column scan: x = (0.97 x + w) * invS[t], 4 cols/thread + prefetch ----------------
__global__ __launch_bounds__(256) void k_colscan(bf16* __restrict__ W,
                                                 const float* __restrict__ invS) {
    __shared__ float sv[TT];
    int b = blockIdx.y;
    sv[threadIdx.x] = invS[b * TT + threadIdx.x];
    __syncthreads();
    int n4 = blockIdx.x * 256 + threadIdx.x;  // uint2 index = 4 bf16 cols
    uint2* p = (uint2*)(W + (long)b * TT * NN) + n4;
    const int STR = NN / 4;  // 1024 uint2 per row
    float x0 = 0.f, x1 = 0.f, x2 = 0.f, x3 = 0.f;
    uint2 cur = p[0];
    for (int t = 0; t < TT; t++) {
        uint2 nxt;
        if (t + 1 < TT) nxt = p[(t + 1) * STR];  // prefetch next row
        float s = sv[t];
        x0 = (DECAY * x0 + bfu2f((short)(cur.x & 0xffff))) * s;
        x1 = (DECAY * x1 + bfu2f((short)(cur.x >> 16))) * s;
        x2 = (DECAY * x2 + bfu2f((short)(cur.y & 0xffff))) * s;
        x3 = (DECAY * x3 + bfu2f((short)(cur.y >> 16))) * s;
        uint2 o;
        o.x = (unsigned)(unsigned short)f2bfu(x0) | ((unsigned)(unsigned short)f2bfu(x1) << 16);
        o.y = (unsigned)(unsigned short)f2bfu(x2) | ((unsigned)(unsigned short)f2bfu(x3) << 16);
        p[t * STR] = o;
        cur = nxt;
    }
}

// ---------------- sum a* partials (1 or 2) + row layernorm -> ALN bf16 ----------------
__global__ __launch_bounds__(256) void k_ln_rows(const bf16* __restrict__ Ap,
                                                 bf16* __restrict__ O) {
    __shared__ float s4[4];
    long r = blockIdx.x;
    int d = threadIdx.x;
    long b = r >> 8, t = r & 255;
    long base = (b * 2) * 65536 + t * 256 + d;
    float z = bfu2f(*(const short*)&Ap[base]);
    if (t >= 128) z += bfu2f(*(const short*)&Ap[base + 65536]);
    float m = blk_sum_256(z, s4) * (1.0f / DD);
    float zc = z - m;
    float var = blk_sum_256(zc * zc, s4) * (1.0f / (DD - 1));
    O[r * DD + d] = __float2bfloat16(zc / (sqrtf(fmaxf(var, 0.f)) + EPS));
}

// ---------------- sum 4 bf16 Z partials + layernorm -> output ----------------
__global__ __launch_bounds__(256) void k_final_ln(const bf16* __restrict__ Zp,
                                                  void* __restrict__ out,
                                                  const int* __restrict__ flag) {
    __shared__ float s4[4];
    long r = blockIdx.x;
    int d = threadIdx.x;
    const long SL = (long)8192 * 256;
    long o = r * DD + d;
    float z = bfu2f(*(const short*)&Zp[o]) + bfu2f(*(const short*)&Zp[o + SL]) +
              bfu2f(*(const short*)&Zp[o + 2 * SL]) + bfu2f(*(const short*)&Zp[o + 3 * SL]);
    float m = blk_sum_256(z, s4) * (1.0f / DD);
    float zc = z - m;
    float var = blk_sum_256(zc * zc, s4) * (1.0f / (DD - 1));
    float v = zc / (sqrtf(fmaxf(var, 0.f)) + EPS);
    if (flag[0]) ((bf16*)out)[o] = __float2bfloat16(v);
    else ((float*)out)[o] = v;
}

extern "C" void kernel_launch(void* const* d_in, const int* in_sizes, int n_in,
                              void* d_out, int out_size, void* d_ws, size_t ws_size,
                              hipStream_t stream) {
    const int* idx = (const int*)d_in[0];
    const void* emb = d_in[1];
    const void* E = d_in[2];
    const void* Dx = d_in[3];
    const void* Dy = d_in[4];

    // ---- workspace carve (bytes) ----
    char* base = (char*)d_ws;
    size_t off = 0;
    int* flag = (int*)base; off += 1024;
    bf16* Dxb = (bf16*)(base + off); off += (size_t)NN * DD * 2;
    bf16* Dyb = (bf16*)(base + off); off += (size_t)NN * DD * 2;
    bf16* Eb  = (bf16*)(base + off); off += (size_t)DD * NN * 2;
    bf16* Vpb = (bf16*)(base + off); off += (size_t)BB * TT * DD * 2;
    bf16* Ub  = (bf16*)(base + off); off += (size_t)BB * TT * DD * 2;
    bf16* Ut  = (bf16*)(base + off); off += (size_t)BB * TT * DD * 2;
    float* Wsum = (float*)(base + off); off += (size_t)BB * TT * 4;
    float* invS = (float*)(base + off); off += (size_t)BB * TT * 4;
    bf16* ALNb = (bf16*)(base + off); off += (size_t)BB * TT * DD * 2;
    bf16* Gp = (bf16*)(base + off); off += (size_t)4 * BB * TT * TT * 2;  // 16.8MB masked bf16 partials
    bf16* Ap = (bf16*)(base + off); off += (size_t)2 * BB * TT * DD * 2;  // 8.4MB a* bf16 partials
    bf16* Zp = Gp;  // Z bf16 partials (4 x 8192 x 256 = 16.8MB) alias Gp (dead after k_astar)
    bf16* Xb = (bf16*)(base + off); off += (size_t)BB * TT * NN * 2;      // 67MB

    const int M = BB * TT;  // 8192

    k_detect<<<1, 256, 0, stream>>>((const unsigned short*)emb, flag);
    k_convert3<<<3 * NN * DD / 8 / 256, 256, 0, stream>>>(Dx, Dy, E, Dxb, Dyb, Eb, flag);
    k_gather_ln<<<M, 256, 0, stream>>>(emb, idx, Vpb, Ub, flag);
    k_transpose<<<dim3(8, 8, BB), 256, 0, stream>>>(Ub, Ut);

    hipMemsetAsync(Wsum, 0, (size_t)M * 4, stream);

    // W = relu(Vp @ Dx^T) -> Xb (bf16), rowsums fused via atomics
    k_fused256<EPI_RELU_BF16><<<dim3(16, 32), 512, 0, stream>>>(Vpb, Dxb, Xb, nullptr, Wsum);

    k_scalar_scan<<<1, 256, 0, stream>>>(Wsum, invS);
    k_colscan<<<dim3(4, BB, 1), 256, 0, stream>>>(Xb, invS);

    // scores partials: 3 lower-triangular tiles, split-K 4, MASKED bf16 partials
    k_mfma_nt<EPI_MASK_BF16, 4, 1, 0><<<dim3(3, 1, BB * 4), 256, 0, stream>>>(
        NN, Xb, NN, (long)TT * NN, Xb, NN, (long)TT * NN, Gp, TT, (long)TT * TT, nullptr, nullptr);

    // a* = (sum of masked partials) @ U
    k_astar<<<dim3(2, 3, BB), 256, 0, stream>>>(Gp, Ut, Ap);
    k_ln_rows<<<M, 256, 0, stream>>>(Ap, ALNb);

    // Y = relu(ALN @ Dy^T) * relu(X), in place over Xb
    k_fused256<EPI_RELU_MULX_BF16><<<dim3(16, 32), 512, 0, stream>>>(ALNb, Dyb, Xb, Xb, nullptr);

    // Z partials = Y @ E^T : BN=256 (Xb read once), split-K 4, bf16 partials into Gp region
    k_zgemm<<<dim3(64, 4), 512, 0, stream>>>(Xb, Eb, Zp);

    k_final_ln<<<M, 256, 0, stream>>>(Zp, d_out, flag);
}

// Round 11
// 325.360 us; speedup vs baseline: 1.0817x; 1.0817x over previous
//
#include <hip/hip_runtime.h>
#include <hip/hip_bf16.h>

#define NN 4096
#define DD 256
#define BB 32
#define TT 256
#define EPS 1e-6f
#define DECAY 0.97f
#define LOG2_DECAY -0.043943348f

typedef __hip_bfloat16 bf16;
typedef short short8 __attribute__((ext_vector_type(8)));
typedef float floatx4 __attribute__((ext_vector_type(4)));

__device__ __forceinline__ float bfu2f(short u) {
    return __uint_as_float(((unsigned)(unsigned short)u) << 16);
}

__device__ __forceinline__ short f2bfu(float f) {
    bf16 t = __float2bfloat16(f);
    return *reinterpret_cast<short*>(&t);
}

// ---------------- block-wide sum over 256 threads ----------------
__device__ __forceinline__ float blk_sum_256(float v, volatile float* s4) {
#pragma unroll
    for (int o = 32; o > 0; o >>= 1) v += __shfl_down(v, o, 64);
    int lane = threadIdx.x & 63, w = threadIdx.x >> 6;
    __syncthreads();
    if (lane == 0) s4[w] = v;
    __syncthreads();
    return s4[0] + s4[1] + s4[2] + s4[3];
}

// async global->LDS, 16B per lane; LDS dest must be wave-uniform base + lane*16
__device__ __forceinline__ void gl16(const bf16* g, bf16* l) {
    __builtin_amdgcn_global_load_lds((const __attribute__((address_space(1))) void*)g,
                                     (__attribute__((address_space(3))) void*)l, 16, 0, 0);
}

// ---------------- dtype detector (bf16-packed vs fp32 inputs) ----------------
__global__ void k_detect(const unsigned short* __restrict__ raw, int* __restrict__ flag) {
    __shared__ int cnt[4];
    int tid = threadIdx.x;
    int bad = 0;
    for (int i = tid; i < 8192; i += 256) {
        unsigned int u = raw[2 * i];
        float v = __uint_as_float(u << 16);
        if (!(fabsf(v) < 1e6f)) bad++;
    }
#pragma unroll
    for (int o = 32; o > 0; o >>= 1) bad += __shfl_down(bad, o, 64);
    int lane = tid & 63, w = tid >> 6;
    if (lane == 0) cnt[w] = bad;
    __syncthreads();
    if (tid == 0) flag[0] = (cnt[0] + cnt[1] + cnt[2] + cnt[3] < 32) ? 1 : 0;
}

// ---------------- convert 3 weight matrices to bf16, 8 elems/thread ----------------
__global__ __launch_bounds__(256) void k_convert3(const void* __restrict__ s0,
                                                  const void* __restrict__ s1,
                                                  const void* __restrict__ s2,
                                                  bf16* __restrict__ d0,
                                                  bf16* __restrict__ d1,
                                                  bf16* __restrict__ d2,
                                                  const int* __restrict__ flag) {
    const int per = NN * DD / 8;  // 131072 16B-chunks per matrix
    int i = blockIdx.x * 256 + threadIdx.x;
    int m = i / per, j = i % per;
    const void* s = (m == 0) ? s0 : (m == 1) ? s1 : s2;
    bf16* d = (m == 0) ? d0 : (m == 1) ? d1 : d2;
    if (flag[0]) {
        ((uint4*)d)[j] = ((const uint4*)s)[j];  // already bf16: straight copy
    } else {
        const float4* f = (const float4*)s;
        float4 a = f[2 * j], b = f[2 * j + 1];
        short8 o;
        float va[8] = {a.x, a.y, a.z, a.w, b.x, b.y, b.z, b.w};
#pragma unroll
        for (int k = 0; k < 8; k++) o[k] = f2bfu(va[k]);
        ((short8*)d)[j] = o;
    }
}

// ---------------- gather embeddings: Vp (raw) and U=LN(row), both bf16 ----------------
__global__ __launch_bounds__(256) void k_gather_ln(const void* __restrict__ emb,
                                                   const int* __restrict__ idx,
                                                   bf16* __restrict__ Vpb,
                                                   bf16* __restrict__ Ub,
                                                   const int* __restrict__ flag) {
    __shared__ float s4[4];
    int r = blockIdx.x, d = threadIdx.x;
    int tok = idx[r];
    long o = (long)tok * DD + d;
    float e = flag[0] ? __bfloat162float(((const bf16*)emb)[o]) : ((const float*)emb)[o];
    Vpb[(long)r * DD + d] = __float2bfloat16(e);
    float m = blk_sum_256(e, s4) * (1.0f / DD);
    float zc = e - m;
    float var = blk_sum_256(zc * zc, s4) * (1.0f / (DD - 1));
    Ub[(long)r * DD + d] = __float2bfloat16(zc / (sqrtf(fmaxf(var, 0.f)) + EPS));
}

// ---------------- per-batch transpose Ub[b][t][d] -> Ut[b][d][t] ----------------
__global__ __launch_bounds__(256) void k_transpose(const bf16* __restrict__ Ub,
                                                   bf16* __restrict__ Ut) {
    __shared__ bf16 tile[32][33];
    int b = blockIdx.z;
    int t0 = blockIdx.x * 32, d0 = blockIdx.y * 32;
    const bf16* src = Ub + (long)b * TT * DD;
    bf16* dst = Ut + (long)b * DD * TT;
    int rr = threadIdx.x >> 3, c4 = (threadIdx.x & 7) * 4;
#pragma unroll
    for (int i = 0; i < 4; i++) tile[rr][c4 + i] = src[(long)(t0 + rr) * DD + d0 + c4 + i];
    __syncthreads();
#pragma unroll
    for (int i = 0; i < 4; i++) dst[(long)(d0 + rr) * TT + t0 + c4 + i] = tile[c4 + i][rr];
}

enum { EPI_RELU_BF16 = 0, EPI_NONE_F32 = 1, EPI_RELU_MULX_BF16 = 2, EPI_NONE_BF16 = 3,
       EPI_MASK_BF16 = 4 };

// ---------------- 256x256-tile K=256 GEMM for W/Y (round-4 v1, best measured) ----------------
template <int EPI>
__global__ __launch_bounds__(512, 2) void k_fused256(const bf16* __restrict__ A,  // M x 256
                                                     const bf16* __restrict__ B,  // N x 256
                                                     bf16* __restrict__ C,        // M x NN
                                                     const bf16* __restrict__ Xaux,
                                                     float* __restrict__ Wsum) {
    __shared__ __align__(16) char smem[65536];  // 2 x (As 16KB | Bs 16KB); epi overlay 33.8KB
    bf16* R = (bf16*)smem;                      // [64][264] repack overlay (post-loop)

    int bx = blockIdx.x, by = blockIdx.y;
    {   // bijective XCD swizzle (nwg = 512, %8 == 0)
        int gx = gridDim.x;
        int nwg = gx * gridDim.y;
        int id = by * gx + bx;
        int q = nwg >> 3;
        int nid = (id & 7) * q + (id >> 3);
        bx = nid % gx;
        by = nid / gx;
    }
    int bm = by * 256, bn = bx * 256;
    int tid = threadIdx.x, wid = tid >> 6, lane = tid & 63;
    int wr = wid >> 2, wc = wid & 3;       // wave grid 2(M) x 4(N); wave tile 128x64
    int lm = lane & 15, kh = lane >> 4;

    int srow2 = tid >> 2;
    int swzcol = (((tid & 3) ^ ((srow2 >> 1) & 3)) << 3);
    const bf16* gA0 = A + (long)(bm + srow2) * DD + swzcol;
    const bf16* gA1 = gA0 + (long)128 * DD;
    const bf16* gB0 = B + (long)(bn + srow2) * DD + swzcol;
    const bf16* gB1 = gB0 + (long)128 * DD;
    int chunk = ((kh ^ ((lm >> 1) & 3)) << 3);

    floatx4 acc[8][4];
#pragma unroll
    for (int i = 0; i < 8; i++)
#pragma unroll
        for (int j = 0; j < 4; j++) acc[i][j] = (floatx4){0.f, 0.f, 0.f, 0.f};

#define STAGE256(SBASE, KK)                             \
    {                                                   \
        bf16* As_ = (bf16*)(SBASE);                     \
        bf16* Bs_ = As_ + 8192;                         \
        gl16(gA0 + (KK), As_ + tid * 8);                \
        gl16(gA1 + (KK), As_ + 4096 + tid * 8);         \
        gl16(gB0 + (KK), Bs_ + tid * 8);                \
        gl16(gB1 + (KK), Bs_ + 4096 + tid * 8);         \
    }

    STAGE256(smem, 0);  // prologue: stage k-step 0 into buffer 0

    int cur = 0;
#pragma unroll
    for (int k0 = 0; k0 < 256; k0 += 32) {
        __builtin_amdgcn_s_barrier();  // prev compute done -> other buffer free
        __builtin_amdgcn_sched_barrier(0);
        if (k0 + 32 < 256) STAGE256(smem + ((cur ^ 1) * 32768), k0 + 32);
        if (k0 + 32 < 256) asm volatile("s_waitcnt vmcnt(4)" ::: "memory");  // stage t landed
        else               asm volatile("s_waitcnt vmcnt(0)" ::: "memory");
        __builtin_amdgcn_s_barrier();  // all waves' stage-t writes visible
        __builtin_amdgcn_sched_barrier(0);
        bf16* cbA = (bf16*)(smem + cur * 32768);
        bf16* cbB = cbA + 8192;
        short8 af[8], bfr[4];
#pragma unroll
        for (int i = 0; i < 8; i++)
            af[i] = *(const short8*)(cbA + (wr * 128 + i * 16 + lm) * 32 + chunk);
#pragma unroll
        for (int j = 0; j < 4; j++)
            bfr[j] = *(const short8*)(cbB + (wc * 64 + j * 16 + lm) * 32 + chunk);
#pragma unroll
        for (int i = 0; i < 8; i++)
#pragma unroll
            for (int j = 0; j < 4; j++)
                acc[i][j] = __builtin_amdgcn_mfma_f32_16x16x32_bf16(af[i], bfr[j], acc[i][j], 0, 0, 0);
        cur ^= 1;
    }
#undef STAGE256

    // ---- LDS-repack epilogue: four 64-row passes, coalesced 16B stores ----
#pragma unroll
    for (int p = 0; p < 4; p++) {
        __syncthreads();
        if (wr == (p >> 1)) {
            int ibase = (p & 1) * 4;
#pragma unroll
            for (int ii = 0; ii < 4; ii++)
#pragma unroll
                for (int j = 0; j < 4; j++)
#pragma unroll
                    for (int r = 0; r < 4; r++) {
                        int rr = ii * 16 + kh * 4 + r;
                        int cc = wc * 64 + j * 16 + lm;
                        R[rr * 264 + cc] = __float2bfloat16(fmaxf(acc[ibase + ii][j][r], 0.f));
                    }
        }
        __syncthreads();
#pragma unroll
        for (int it = 0; it < 4; it++) {
            int row_l = it * 16 + (tid >> 5);
            int c8 = (tid & 31) * 8;
            short8 vv = *(const short8*)(R + row_l * 264 + c8);
            int gm = bm + p * 64 + row_l;
            long off = (long)gm * NN + bn + c8;
            if (EPI == EPI_RELU_BF16) {
                *(short8*)(C + off) = vv;
                float s = 0.f;
#pragma unroll
                for (int k = 0; k < 8; k++) s += bfu2f(vv[k]);
#pragma unroll
                for (int o = 16; o > 0; o >>= 1) s += __shfl_down(s, o, 32);
                if ((tid & 31) == 0) atomicAdd(&Wsum[gm], s);
            } else {  // EPI_RELU_MULX_BF16
                short8 xx = *(const short8*)(Xaux + off);
                short8 oo;
#pragma unroll
                for (int k = 0; k < 8; k++) {
                    float prod = bfu2f(vv[k]) * fmaxf(bfu2f(xx[k]), 0.f);
                    oo[k] = f2bfu(prod);
                }
                *(short8*)(C + off) = oo;
            }
        }
    }
}

// ---------------- MFMA bf16 NT GEMM (long-K path): triple-buffered counted ----------------
template <int EPI, int KSPLIT, int TRI, int SWZ>
__global__ __launch_bounds__(256) void k_mfma_nt(int K,
                                                 const bf16* __restrict__ A, int lda, long sA,
                                                 const bf16* __restrict__ B, int ldb, long sB,
                                                 void* __restrict__ Cv, int ldc, long sC,
                                                 const bf16* __restrict__ Xaux,
                                                 float* __restrict__ Wsum) {
    __shared__ __align__(16) char smem[49152];  // 3 x (As 8KB | Bs 8KB)
    bf16* R = (bf16*)smem;  // [64][136] repack buffer (overlays buffers, used post-loop)

    int z = blockIdx.z;
    int bz = z / KSPLIT, ks = z % KSPLIT;
    A += (long)bz * sA;
    B += (long)bz * sB;
    int bx = blockIdx.x, by = blockIdx.y;
    if (TRI) {  // 3-tile lower-triangular mapping: 0->(0,0) 1->(1,0) 2->(1,1)
        by = (blockIdx.x >= 1) ? 1 : 0;
        bx = (blockIdx.x == 2) ? 1 : 0;
    }
    if (SWZ) {  // bijective XCD swizzle over the xy-plane (requires nwg%8==0)
        int gx = gridDim.x;
        int nwg = gx * gridDim.y;
        int id = by * gx + bx;
        int q = nwg >> 3;
        int nid = (id & 7) * q + (id >> 3);
        bx = nid % gx;
        by = nid / gx;
    }
    int bm = by * 128, bn = bx * 128;
    int tid = threadIdx.x;
    int srow = tid >> 2;
    int scol = ((((srow >> 1) & 3) ^ (tid & 3)) << 3);
    int w = tid >> 6, lane = tid & 63;
    int wm = (w >> 1) * 64, wn = (w & 1) * 64;
    int lm = lane & 15, kh = lane >> 4;

    floatx4 acc[4][4];
#pragma unroll
    for (int i = 0; i < 4; i++)
#pragma unroll
        for (int j = 0; j < 4; j++) acc[i][j] = (floatx4){0.f, 0.f, 0.f, 0.f};

    int kchunk = K / KSPLIT;
    int kbeg = ks * kchunk, kend = kbeg + kchunk;
    const bf16* gA0 = A + (long)(bm + srow) * lda + scol;
    const bf16* gA1 = gA0 + (long)64 * lda;
    const bf16* gB0 = B + (long)(bn + srow) * ldb + scol;
    const bf16* gB1 = gB0 + (long)64 * ldb;
    int dslot = tid * 8;  // bf16 elements

#define STAGE_SLOT(SBASE, KK)                          \
    {                                                  \
        bf16* bufA = (bf16*)(SBASE);                   \
        bf16* bufB = bufA + 4096;                      \
        gl16(gA0 + (KK), bufA + dslot);                \
        gl16(gA1 + (KK), bufA + 2048 + dslot);         \
        gl16(gB0 + (KK), bufB + dslot);                \
        gl16(gB1 + (KK), bufB + 2048 + dslot);         \
    }

    // prologue: prefetch distance 2
    STAGE_SLOT(smem, kbeg);
    if (kbeg + 32 < kend) STAGE_SLOT(smem + 16384, kbeg + 32);

    int cur = 0;
    for (int k0 = kbeg; k0 < kend; k0 += 32) {
        __builtin_amdgcn_s_barrier();
        __builtin_amdgcn_sched_barrier(0);
        if (k0 + 64 < kend) {
            int ps = (cur == 0) ? 2 : cur - 1;  // (cur+2)%3
            STAGE_SLOT(smem + ps * 16384, k0 + 64);
        }
        int rem = (kend - k0 - 32) >> 5;
        if (rem >= 2)      asm volatile("s_waitcnt vmcnt(8)" ::: "memory");
        else if (rem == 1) asm volatile("s_waitcnt vmcnt(4)" ::: "memory");
        else               asm volatile("s_waitcnt vmcnt(0)" ::: "memory");
        __builtin_amdgcn_s_barrier();
        __builtin_amdgcn_sched_barrier(0);
        bf16* cbA = (bf16*)(smem + cur * 16384);
        bf16* cbB = cbA + 4096;
        short8 af[4], bfr[4];
#pragma unroll
        for (int i = 0; i < 4; i++) {
            int row = wm + i * 16 + lm;
            af[i] = *(const short8*)(cbA + row * 32 + ((((row >> 1) & 3) ^ kh) << 3));
        }
#pragma unroll
        for (int j = 0; j < 4; j++) {
            int row = wn + j * 16 + lm;
            bfr[j] = *(const short8*)(cbB + row * 32 + ((((row >> 1) & 3) ^ kh) << 3));
        }
#pragma unroll
        for (int i = 0; i < 4; i++)
#pragma unroll
            for (int j = 0; j < 4; j++)
                acc[i][j] = __builtin_amdgcn_mfma_f32_16x16x32_bf16(af[i], bfr[j], acc[i][j], 0, 0, 0);
        cur = (cur == 2) ? 0 : cur + 1;
    }
#undef STAGE_SLOT

    if (EPI == EPI_NONE_F32) {
        long cbase = (long)z * sC;
#pragma unroll
        for (int i = 0; i < 4; i++)
#pragma unroll
            for (int j = 0; j < 4; j++)
#pragma unroll
                for (int r = 0; r < 4; r++) {
                    int gm = bm + wm + i * 16 + kh * 4 + r;
                    int gn = bn + wn + j * 16 + lm;
                    ((float*)Cv)[cbase + (long)gm * ldc + gn] = acc[i][j][r];
                }
        return;
    }

    // ---- LDS-repack epilogue: two 64-row passes, coalesced 16B stores ----
    bf16* Cb = (bf16*)Cv + (long)z * sC;
#pragma unroll
    for (int p = 0; p < 2; p++) {
        __syncthreads();
        if ((w >> 1) == p) {
#pragma unroll
            for (int i = 0; i < 4; i++)
#pragma unroll
                for (int j = 0; j < 4; j++)
#pragma unroll
                    for (int r = 0; r < 4; r++) {
                        int rr = i * 16 + kh * 4 + r;
                        int cc = wn + j * 16 + lm;
                        float val = acc[i][j][r];
                        if (EPI == EPI_RELU_BF16 || EPI == EPI_RELU_MULX_BF16) val = fmaxf(val, 0.f);
                        R[rr * 136 + cc] = __float2bfloat16(val);
                    }
        }
        __syncthreads();
#pragma unroll
        for (int it = 0; it < 4; it++) {
            int row_l = it * 16 + (tid >> 4);
            int c8 = (tid & 15) * 8;
            short8 vv = *(const short8*)(R + row_l * 136 + c8);
            int gm = bm + p * 64 + row_l;
            long off = (long)gm * ldc + bn + c8;
            if (EPI == EPI_NONE_BF16) {
                *(short8*)(Cb + off) = vv;
            } else if (EPI == EPI_MASK_BF16) {
                short8 oo;
#pragma unroll
                for (int k = 0; k < 8; k++) {
                    int s = bn + c8 + k;
                    float f = bfu2f(vv[k]);
                    f = (s < gm) ? f * exp2f((float)(gm - s) * LOG2_DECAY) : 0.f;
                    oo[k] = f2bfu(f);
                }
                *(short8*)(Cb + off) = oo;
            } else if (EPI == EPI_RELU_BF16) {
                *(short8*)(Cb + off) = vv;
                float s = 0.f;
#pragma unroll
                for (int k = 0; k < 8; k++) s += bfu2f(vv[k]);
#pragma unroll
                for (int o = 8; o > 0; o >>= 1) s += __shfl_down(s, o, 16);
                if ((tid & 15) == 0) atomicAdd(&Wsum[gm], s);
            } else {  // EPI_RELU_MULX_BF16
                short8 xx = *(const short8*)(Xaux + off);
                short8 oo;
#pragma unroll
                for (int k = 0; k < 8; k++) {
                    float prod = bfu2f(vv[k]) * fmaxf(bfu2f(xx[k]), 0.f);
                    oo[k] = f2bfu(prod);
                }
                *(short8*)(Cb + off) = oo;
            }
        }
    }
}

// ---------------- a* GEMM: A = sum of 4 masked bf16 score partials (reg-staged), B = Ut ----------------
__global__ __launch_bounds__(256) void k_astar(const bf16* __restrict__ Gp,
                                               const bf16* __restrict__ Ut,
                                               bf16* __restrict__ Ap) {
    __shared__ __align__(16) char smem[32768];
    bf16* R = (bf16*)smem;

    int b = blockIdx.z;
    int y = blockIdx.y;
    int by = (y >= 1) ? 1 : 0, ks = (y == 2) ? 1 : 0;
    int bx = blockIdx.x;
    int bm = by * 128, bn = bx * 128, kbeg = ks * 128;
    int tid = threadIdx.x;
    int srow = tid >> 2;
    int scol = ((((srow >> 1) & 3) ^ (tid & 3)) << 3);
    int w = tid >> 6, lane = tid & 63;
    int wm = (w >> 1) * 64, wn = (w & 1) * 64;
    int lm = lane & 15, kh = lane >> 4;

    const bf16* gA = Gp + (long)b * 4 * 65536;
    long aoff0 = (long)(bm + srow) * TT + scol + kbeg;
    long aoff1 = (long)(bm + srow + 64) * TT + scol + kbeg;
    const bf16* gB0 = Ut + (long)b * DD * TT + (long)(bn + srow) * TT + scol + kbeg;
    const bf16* gB1 = gB0 + (long)64 * TT;
    int dslot = tid * 8;

    floatx4 acc[4][4];
#pragma unroll
    for (int i = 0; i < 4; i++)
#pragma unroll
        for (int j = 0; j < 4; j++) acc[i][j] = (floatx4){0.f, 0.f, 0.f, 0.f};

#define LOAD4SUM(DST, AOFF)                                        \
    {                                                              \
        short8 p0 = *(const short8*)(gA + (AOFF));                 \
        short8 p1 = *(const short8*)(gA + 65536 + (AOFF));         \
        short8 p2 = *(const short8*)(gA + 2 * 65536 + (AOFF));     \
        short8 p3 = *(const short8*)(gA + 3 * 65536 + (AOFF));     \
        short8 o_;                                                 \
        _Pragma("unroll")                                          \
        for (int k_ = 0; k_ < 8; k_++)                             \
            o_[k_] = f2bfu(bfu2f(p0[k_]) + bfu2f(p1[k_]) +         \
                           bfu2f(p2[k_]) + bfu2f(p3[k_]));         \
        DST = o_;                                                  \
    }

    {
        bf16* As_ = (bf16*)smem;
        bf16* Bs_ = As_ + 4096;
        gl16(gB0, Bs_ + dslot);
        gl16(gB1, Bs_ + 2048 + dslot);
        short8 ra0, ra1;
        LOAD4SUM(ra0, aoff0);
        LOAD4SUM(ra1, aoff1);
        *(short8*)(As_ + dslot) = ra0;
        *(short8*)(As_ + 2048 + dslot) = ra1;
    }
    __syncthreads();

    int cur = 0;
    for (int kk = 0; kk < 128; kk += 32) {
        bf16* cbA = (bf16*)(smem + cur * 16384);
        bf16* cbB = cbA + 4096;
        bf16* nbA = (bf16*)(smem + (cur ^ 1) * 16384);
        bf16* nbB = nbA + 4096;
        short8 na0, na1;
        bool has = (kk + 32) < 128;
        if (has) {
            gl16(gB0 + kk + 32, nbB + dslot);
            gl16(gB1 + kk + 32, nbB + 2048 + dslot);
            LOAD4SUM(na0, aoff0 + kk + 32);
            LOAD4SUM(na1, aoff1 + kk + 32);
        }
        short8 af[4], bfr[4];
#pragma unroll
        for (int i = 0; i < 4; i++) {
            int row = wm + i * 16 + lm;
            af[i] = *(const short8*)(cbA + row * 32 + ((((row >> 1) & 3) ^ kh) << 3));
        }
#pragma unroll
        for (int j = 0; j < 4; j++) {
            int row = wn + j * 16 + lm;
            bfr[j] = *(const short8*)(cbB + row * 32 + ((((row >> 1) & 3) ^ kh) << 3));
        }
#pragma unroll
        for (int i = 0; i < 4; i++)
#pragma unroll
            for (int j = 0; j < 4; j++)
                acc[i][j] = __builtin_amdgcn_mfma_f32_16x16x32_bf16(af[i], bfr[j], acc[i][j], 0, 0, 0);
        if (has) {
            *(short8*)(nbA + dslot) = na0;
            *(short8*)(nbA + 2048 + dslot) = na1;
        }
        __syncthreads();
        cur ^= 1;
    }
#undef LOAD4SUM

    bf16* Cb = Ap + ((long)b * 2 + ks) * 65536;
#pragma unroll
    for (int p = 0; p < 2; p++) {
        __syncthreads();
        if ((w >> 1) == p) {
#pragma unroll
            for (int i = 0; i < 4; i++)
#pragma unroll
                for (int j = 0; j < 4; j++)
#pragma unroll
                    for (int r = 0; r < 4; r++) {
                        int rr = i * 16 + kh * 4 + r;
                        int cc = wn + j * 16 + lm;
                        R[rr * 136 + cc] = __float2bfloat16(acc[i][j][r]);
                    }
        }
        __syncthreads();
#pragma unroll
        for (int it = 0; it < 4; it++) {
            int row_l = it * 16 + (tid >> 4);
            int c8 = (tid & 15) * 8;
            short8 vv = *(const short8*)(R + row_l * 136 + c8);
            int gm = bm + p * 64 + row_l;
            *(short8*)(Cb + (long)gm * DD + bn + c8) = vv;
        }
    }
}

// ---------------- scalar normalizer recurrence ----------------
__global__ __launch_bounds__(256) void k_scalar_scan(const float* __restrict__ Wsum,
                                                     float* __restrict__ invS) {
    __shared__ float sw[BB * TT];
    for (int i = threadIdx.x; i < BB * TT; i += 256) sw[i] = Wsum[i];
    __syncthreads();
    int b = threadIdx.x;
    if (b < BB) {
        float sig = 0.f;
        for (int t = 0; t < TT; t++) {
            float S = DECAY * sig + sw[b * TT + t];
            float inv = 1.f / (S + EPS);
            invS[b * TT + t] = inv;
            sig = S * inv;
        }
    }
}

// ---------------- barrier-free column scan: x = (0.97 x + w) * invS[t] ----------------
__global__ __launch_bounds__(256) void k_colscan(bf16* __restrict__ W,
                                                 const float* __restrict__ invS) {
    __shared__ float sv[TT];
    int b = blockIdx.y;
    sv[threadIdx.x] = invS[b * TT + threadIdx.x];
    __syncthreads();
    int n = blockIdx.x * 256 + threadIdx.x;
    bf16* p = W + (long)b * TT * NN + n;
    float x = 0.f;
    for (int t = 0; t < TT; t++) {
        float w = __bfloat162float(p[(long)t * NN]);
        x = (DECAY * x + w) * sv[t];
        p[(long)t * NN] = __float2bfloat16(x);
    }
}

// ---------------- sum a* partials (1 or 2) + row layernorm -> ALN bf16 ----------------
__global__ __launch_bounds__(256) void k_ln_rows(const bf16* __restrict__ Ap,
                                                 bf16* __restrict__ O) {
    __shared__ float s4[4];
    long r = blockIdx.x;
    int d = threadIdx.x;
    long b = r >> 8, t = r & 255;
    long base = (b * 2) * 65536 + t * 256 + d;
    float z = bfu2f(*(const short*)&Ap[base]);
    if (t >= 128) z += bfu2f(*(const short*)&Ap[base + 65536]);
    float m = blk_sum_256(z, s4) * (1.0f / DD);
    float zc = z - m;
    float var = blk_sum_256(zc * zc, s4) * (1.0f / (DD - 1));
    O[r * DD + d] = __float2bfloat16(zc / (sqrtf(fmaxf(var, 0.f)) + EPS));
}

// ---------------- sum 2 split-K Z partials + layernorm -> output ----------------
__global__ __launch_bounds__(256) void k_final_ln(const float* __restrict__ Zp,
                                                  void* __restrict__ out,
                                                  const int* __restrict__ flag) {
    __shared__ float s4[4];
    long r = blockIdx.x;
    int d = threadIdx.x;
    const long SL = (long)8192 * 256;
    long o = r * DD + d;
    float z = Zp[o] + Zp[o + SL];
    float m = blk_sum_256(z, s4) * (1.0f / DD);
    float zc = z - m;
    float var = blk_sum_256(zc * zc, s4) * (1.0f / (DD - 1));
    float v = zc / (sqrtf(fmaxf(var, 0.f)) + EPS);
    if (flag[0]) ((bf16*)out)[o] = __float2bfloat16(v);
    else ((float*)out)[o] = v;
}

extern "C" void kernel_launch(void* const* d_in, const int* in_sizes, int n_in,
                              void* d_out, int out_size, void* d_ws, size_t ws_size,
                              hipStream_t stream) {
    const int* idx = (const int*)d_in[0];
    const void* emb = d_in[1];
    const void* E = d_in[2];
    const void* Dx = d_in[3];
    const void* Dy = d_in[4];

    // ---- workspace carve (bytes) ----
    char* base = (char*)d_ws;
    size_t off = 0;
    int* flag = (int*)base; off += 1024;
    bf16* Dxb = (bf16*)(base + off); off += (size_t)NN * DD * 2;
    bf16* Dyb = (bf16*)(base + off); off += (size_t)NN * DD * 2;
    bf16* Eb  = (bf16*)(base + off); off += (size_t)DD * NN * 2;
    bf16* Vpb = (bf16*)(base + off); off += (size_t)BB * TT * DD * 2;
    bf16* Ub  = (bf16*)(base + off); off += (size_t)BB * TT * DD * 2;
    bf16* Ut  = (bf16*)(base + off); off += (size_t)BB * TT * DD * 2;
    float* Wsum = (float*)(base + off); off += (size_t)BB * TT * 4;
    float* invS = (float*)(base + off); off += (size_t)BB * TT * 4;
    bf16* ALNb = (bf16*)(base + off); off += (size_t)BB * TT * DD * 2;
    bf16* Gp = (bf16*)(base + off); off += (size_t)4 * BB * TT * TT * 2;  // 16.8MB masked bf16 partials
    bf16* Ap = (bf16*)(base + off); off += (size_t)2 * BB * TT * DD * 2;  // 8.4MB a* bf16 partials
    float* Zp = (float*)Gp;  // Z f32 partials alias Gp (dead after k_astar; 2x8.4MB fits)
    bf16* Xb = (bf16*)(base + off); off += (size_t)BB * TT * NN * 2;      // 67MB

    const int M = BB * TT;  // 8192

    k_detect<<<1, 256, 0, stream>>>((const unsigned short*)emb, flag);
    k_convert3<<<3 * NN * DD / 8 / 256, 256, 0, stream>>>(Dx, Dy, E, Dxb, Dyb, Eb, flag);
    k_gather_ln<<<M, 256, 0, stream>>>(emb, idx, Vpb, Ub, flag);
    k_transpose<<<dim3(8, 8, BB), 256, 0, stream>>>(Ub, Ut);

    hipMemsetAsync(Wsum, 0, (size_t)M * 4, stream);

    // W = relu(Vp @ Dx^T) -> Xb (bf16), rowsums fused via atomics
    k_fused256<EPI_RELU_BF16><<<dim3(16, 32), 512, 0, stream>>>(Vpb, Dxb, Xb, nullptr, Wsum);

    k_scalar_scan<<<1, 256, 0, stream>>>(Wsum, invS);
    k_colscan<<<dim3(16, BB, 1), 256, 0, stream>>>(Xb, invS);

    // scores partials: 3 lower-triangular tiles, split-K 4, MASKED bf16 partials
    k_mfma_nt<EPI_MASK_BF16, 4, 1, 0><<<dim3(3, 1, BB * 4), 256, 0, stream>>>(
        NN, Xb, NN, (long)TT * NN, Xb, NN, (long)TT * NN, Gp, TT, (long)TT * TT, nullptr, nullptr);

    // a* = (sum of masked partials) @ U
    k_astar<<<dim3(2, 3, BB), 256, 0, stream>>>(Gp, Ut, Ap);
    k_ln_rows<<<M, 256, 0, stream>>>(Ap, ALNb);

    // Y = relu(ALN @ Dy^T) * relu(X), in place over Xb
    k_fused256<EPI_RELU_MULX_BF16><<<dim3(16, 32), 512, 0, stream>>>(ALNb, Dyb, Xb, Xb, nullptr);

    // Z partials = Y @ E^T (split-K 2, f32 partials into Gp region)
    k_mfma_nt<EPI_NONE_F32, 2, 0, 1><<<dim3(2, 64, 2), 256, 0, stream>>>(
        NN, Xb, NN, 0, Eb, NN, 0, Zp, DD, (long)M * DD, nullptr, nullptr);

    k_final_ln<<<M, 256, 0, stream>>>(Zp, d_out, flag);
}

// Round 12
// 308.501 us; speedup vs baseline: 1.1408x; 1.0547x over previous
//
#include <hip/hip_runtime.h>
#include <hip/hip_bf16.h>

#define NN 4096
#define DD 256
#define BB 32
#define TT 256
#define EPS 1e-6f
#define DECAY 0.97f
#define LOG2_DECAY -0.043943348f

typedef __hip_bfloat16 bf16;
typedef short short8 __attribute__((ext_vector_type(8)));
typedef float floatx4 __attribute__((ext_vector_type(4)));

__device__ __forceinline__ float bfu2f(short u) {
    return __uint_as_float(((unsigned)(unsigned short)u) << 16);
}

__device__ __forceinline__ short f2bfu(float f) {
    bf16 t = __float2bfloat16(f);
    return *reinterpret_cast<short*>(&t);
}

// ---------------- block-wide sum over 256 threads ----------------
__device__ __forceinline__ float blk_sum_256(float v, volatile float* s4) {
#pragma unroll
    for (int o = 32; o > 0; o >>= 1) v += __shfl_down(v, o, 64);
    int lane = threadIdx.x & 63, w = threadIdx.x >> 6;
    __syncthreads();
    if (lane == 0) s4[w] = v;
    __syncthreads();
    return s4[0] + s4[1] + s4[2] + s4[3];
}

// async global->LDS, 16B per lane; LDS dest must be wave-uniform base + lane*16
__device__ __forceinline__ void gl16(const bf16* g, bf16* l) {
    __builtin_amdgcn_global_load_lds((const __attribute__((address_space(1))) void*)g,
                                     (__attribute__((address_space(3))) void*)l, 16, 0, 0);
}

// ---------------- dtype detector (bf16-packed vs fp32 inputs) ----------------
__global__ void k_detect(const unsigned short* __restrict__ raw, int* __restrict__ flag) {
    __shared__ int cnt[4];
    int tid = threadIdx.x;
    int bad = 0;
    for (int i = tid; i < 8192; i += 256) {
        unsigned int u = raw[2 * i];
        float v = __uint_as_float(u << 16);
        if (!(fabsf(v) < 1e6f)) bad++;
    }
#pragma unroll
    for (int o = 32; o > 0; o >>= 1) bad += __shfl_down(bad, o, 64);
    int lane = tid & 63, w = tid >> 6;
    if (lane == 0) cnt[w] = bad;
    __syncthreads();
    if (tid == 0) flag[0] = (cnt[0] + cnt[1] + cnt[2] + cnt[3] < 32) ? 1 : 0;
}

// ---------------- convert 3 weight matrices to bf16, 8 elems/thread ----------------
__global__ __launch_bounds__(256) void k_convert3(const void* __restrict__ s0,
                                                  const void* __restrict__ s1,
                                                  const void* __restrict__ s2,
                                                  bf16* __restrict__ d0,
                                                  bf16* __restrict__ d1,
                                                  bf16* __restrict__ d2,
                                                  const int* __restrict__ flag) {
    const int per = NN * DD / 8;  // 131072 16B-chunks per matrix
    int i = blockIdx.x * 256 + threadIdx.x;
    int m = i / per, j = i % per;
    const void* s = (m == 0) ? s0 : (m == 1) ? s1 : s2;
    bf16* d = (m == 0) ? d0 : (m == 1) ? d1 : d2;
    if (flag[0]) {
        ((uint4*)d)[j] = ((const uint4*)s)[j];  // already bf16: straight copy
    } else {
        const float4* f = (const float4*)s;
        float4 a = f[2 * j], b = f[2 * j + 1];
        short8 o;
        float va[8] = {a.x, a.y, a.z, a.w, b.x, b.y, b.z, b.w};
#pragma unroll
        for (int k = 0; k < 8; k++) o[k] = f2bfu(va[k]);
        ((short8*)d)[j] = o;
    }
}

// ---------------- gather embeddings: Vp (raw) and U=LN(row), both bf16 ----------------
__global__ __launch_bounds__(256) void k_gather_ln(const void* __restrict__ emb,
                                                   const int* __restrict__ idx,
                                                   bf16* __restrict__ Vpb,
                                                   bf16* __restrict__ Ub,
                                                   const int* __restrict__ flag) {
    __shared__ float s4[4];
    int r = blockIdx.x, d = threadIdx.x;
    int tok = idx[r];
    long o = (long)tok * DD + d;
    float e = flag[0] ? __bfloat162float(((const bf16*)emb)[o]) : ((const float*)emb)[o];
    Vpb[(long)r * DD + d] = __float2bfloat16(e);
    float m = blk_sum_256(e, s4) * (1.0f / DD);
    float zc = e - m;
    float var = blk_sum_256(zc * zc, s4) * (1.0f / (DD - 1));
    Ub[(long)r * DD + d] = __float2bfloat16(zc / (sqrtf(fmaxf(var, 0.f)) + EPS));
}

// ---------------- per-batch transpose Ub[b][t][d] -> Ut[b][d][t] ----------------
__global__ __launch_bounds__(256) void k_transpose(const bf16* __restrict__ Ub,
                                                   bf16* __restrict__ Ut) {
    __shared__ bf16 tile[32][33];
    int b = blockIdx.z;
    int t0 = blockIdx.x * 32, d0 = blockIdx.y * 32;
    const bf16* src = Ub + (long)b * TT * DD;
    bf16* dst = Ut + (long)b * DD * TT;
    int rr = threadIdx.x >> 3, c4 = (threadIdx.x & 7) * 4;
#pragma unroll
    for (int i = 0; i < 4; i++) tile[rr][c4 + i] = src[(long)(t0 + rr) * DD + d0 + c4 + i];
    __syncthreads();
#pragma unroll
    for (int i = 0; i < 4; i++) dst[(long)(d0 + rr) * TT + t0 + c4 + i] = tile[c4 + i][rr];
}

enum { EPI_RELU_BF16 = 0, EPI_NONE_F32 = 1, EPI_RELU_MULX_BF16 = 2, EPI_NONE_BF16 = 3,
       EPI_MASK_BF16 = 4 };

// ---------------- 256x256-tile K=256 GEMM for W/Y (round-4 v1, best measured) ----------------
template <int EPI>
__global__ __launch_bounds__(512, 2) void k_fused256(const bf16* __restrict__ A,  // M x 256
                                                     const bf16* __restrict__ B,  // N x 256
                                                     bf16* __restrict__ C,        // M x NN
                                                     const bf16* __restrict__ Xaux,
                                                     float* __restrict__ Wsum) {
    __shared__ __align__(16) char smem[65536];  // 2 x (As 16KB | Bs 16KB); epi overlay 33.8KB
    bf16* R = (bf16*)smem;                      // [64][264] repack overlay (post-loop)

    int bx = blockIdx.x, by = blockIdx.y;
    {   // bijective XCD swizzle (nwg = 512, %8 == 0)
        int gx = gridDim.x;
        int nwg = gx * gridDim.y;
        int id = by * gx + bx;
        int q = nwg >> 3;
        int nid = (id & 7) * q + (id >> 3);
        bx = nid % gx;
        by = nid / gx;
    }
    int bm = by * 256, bn = bx * 256;
    int tid = threadIdx.x, wid = tid >> 6, lane = tid & 63;
    int wr = wid >> 2, wc = wid & 3;       // wave grid 2(M) x 4(N); wave tile 128x64
    int lm = lane & 15, kh = lane >> 4;

    int srow2 = tid >> 2;
    int swzcol = (((tid & 3) ^ ((srow2 >> 1) & 3)) << 3);
    const bf16* gA0 = A + (long)(bm + srow2) * DD + swzcol;
    const bf16* gA1 = gA0 + (long)128 * DD;
    const bf16* gB0 = B + (long)(bn + srow2) * DD + swzcol;
    const bf16* gB1 = gB0 + (long)128 * DD;
    int chunk = ((kh ^ ((lm >> 1) & 3)) << 3);

    floatx4 acc[8][4];
#pragma unroll
    for (int i = 0; i < 8; i++)
#pragma unroll
        for (int j = 0; j < 4; j++) acc[i][j] = (floatx4){0.f, 0.f, 0.f, 0.f};

#define STAGE256(SBASE, KK)                             \
    {                                                   \
        bf16* As_ = (bf16*)(SBASE);                     \
        bf16* Bs_ = As_ + 8192;                         \
        gl16(gA0 + (KK), As_ + tid * 8);                \
        gl16(gA1 + (KK), As_ + 4096 + tid * 8);         \
        gl16(gB0 + (KK), Bs_ + tid * 8);                \
        gl16(gB1 + (KK), Bs_ + 4096 + tid * 8);         \
    }

    STAGE256(smem, 0);  // prologue: stage k-step 0 into buffer 0

    int cur = 0;
#pragma unroll
    for (int k0 = 0; k0 < 256; k0 += 32) {
        __builtin_amdgcn_s_barrier();  // prev compute done -> other buffer free
        __builtin_amdgcn_sched_barrier(0);
        if (k0 + 32 < 256) STAGE256(smem + ((cur ^ 1) * 32768), k0 + 32);
        if (k0 + 32 < 256) asm volatile("s_waitcnt vmcnt(4)" ::: "memory");  // stage t landed
        else               asm volatile("s_waitcnt vmcnt(0)" ::: "memory");
        __builtin_amdgcn_s_barrier();  // all waves' stage-t writes visible
        __builtin_amdgcn_sched_barrier(0);
        bf16* cbA = (bf16*)(smem + cur * 32768);
        bf16* cbB = cbA + 8192;
        short8 af[8], bfr[4];
#pragma unroll
        for (int i = 0; i < 8; i++)
            af[i] = *(const short8*)(cbA + (wr * 128 + i * 16 + lm) * 32 + chunk);
#pragma unroll
        for (int j = 0; j < 4; j++)
            bfr[j] = *(const short8*)(cbB + (wc * 64 + j * 16 + lm) * 32 + chunk);
#pragma unroll
        for (int i = 0; i < 8; i++)
#pragma unroll
            for (int j = 0; j < 4; j++)
                acc[i][j] = __builtin_amdgcn_mfma_f32_16x16x32_bf16(af[i], bfr[j], acc[i][j], 0, 0, 0);
        cur ^= 1;
    }
#undef STAGE256

    // ---- LDS-repack epilogue: four 64-row passes, coalesced 16B stores ----
#pragma unroll
    for (int p = 0; p < 4; p++) {
        __syncthreads();
        if (wr == (p >> 1)) {
            int ibase = (p & 1) * 4;
#pragma unroll
            for (int ii = 0; ii < 4; ii++)
#pragma unroll
                for (int j = 0; j < 4; j++)
#pragma unroll
                    for (int r = 0; r < 4; r++) {
                        int rr = ii * 16 + kh * 4 + r;
                        int cc = wc * 64 + j * 16 + lm;
                        R[rr * 264 + cc] = __float2bfloat16(fmaxf(acc[ibase + ii][j][r], 0.f));
                    }
        }
        __syncthreads();
#pragma unroll
        for (int it = 0; it < 4; it++) {
            int row_l = it * 16 + (tid >> 5);
            int c8 = (tid & 31) * 8;
            short8 vv = *(const short8*)(R + row_l * 264 + c8);
            int gm = bm + p * 64 + row_l;
            long off = (long)gm * NN + bn + c8;
            if (EPI == EPI_RELU_BF16) {
                *(short8*)(C + off) = vv;
                float s = 0.f;
#pragma unroll
                for (int k = 0; k < 8; k++) s += bfu2f(vv[k]);
#pragma unroll
                for (int o = 16; o > 0; o >>= 1) s += __shfl_down(s, o, 32);
                if ((tid & 31) == 0) atomicAdd(&Wsum[gm], s);
            } else {  // EPI_RELU_MULX_BF16
                short8 xx = *(const short8*)(Xaux + off);
                short8 oo;
#pragma unroll
                for (int k = 0; k < 8; k++) {
                    float prod = bfu2f(vv[k]) * fmaxf(bfu2f(xx[k]), 0.f);
                    oo[k] = f2bfu(prod);
                }
                *(short8*)(C + off) = oo;
            }
        }
    }
}

// ---------------- MFMA bf16 NT GEMM (long-K path): triple-buffered counted ----------------
template <int EPI, int KSPLIT, int TRI, int SWZ>
__global__ __launch_bounds__(256) void k_mfma_nt(int K,
                                                 const bf16* __restrict__ A, int lda, long sA,
                                                 const bf16* __restrict__ B, int ldb, long sB,
                                                 void* __restrict__ Cv, int ldc, long sC,
                                                 const bf16* __restrict__ Xaux,
                                                 float* __restrict__ Wsum) {
    __shared__ __align__(16) char smem[49152];  // 3 x (As 8KB | Bs 8KB)
    bf16* R = (bf16*)smem;  // [64][136] repack buffer (overlays buffers, used post-loop)

    int z = blockIdx.z;
    int bz = z / KSPLIT, ks = z % KSPLIT;
    A += (long)bz * sA;
    B += (long)bz * sB;
    int bx = blockIdx.x, by = blockIdx.y;
    if (TRI) {  // 3-tile lower-triangular mapping: 0->(0,0) 1->(1,0) 2->(1,1)
        by = (blockIdx.x >= 1) ? 1 : 0;
        bx = (blockIdx.x == 2) ? 1 : 0;
    }
    if (SWZ) {  // bijective XCD swizzle over the xy-plane (requires nwg%8==0)
        int gx = gridDim.x;
        int nwg = gx * gridDim.y;
        int id = by * gx + bx;
        int q = nwg >> 3;
        int nid = (id & 7) * q + (id >> 3);
        bx = nid % gx;
        by = nid / gx;
    }
    int bm = by * 128, bn = bx * 128;
    int tid = threadIdx.x;
    int srow = tid >> 2;
    int scol = ((((srow >> 1) & 3) ^ (tid & 3)) << 3);
    int w = tid >> 6, lane = tid & 63;
    int wm = (w >> 1) * 64, wn = (w & 1) * 64;
    int lm = lane & 15, kh = lane >> 4;

    floatx4 acc[4][4];
#pragma unroll
    for (int i = 0; i < 4; i++)
#pragma unroll
        for (int j = 0; j < 4; j++) acc[i][j] = (floatx4){0.f, 0.f, 0.f, 0.f};

    int kchunk = K / KSPLIT;
    int kbeg = ks * kchunk, kend = kbeg + kchunk;
    const bf16* gA0 = A + (long)(bm + srow) * lda + scol;
    const bf16* gA1 = gA0 + (long)64 * lda;
    const bf16* gB0 = B + (long)(bn + srow) * ldb + scol;
    const bf16* gB1 = gB0 + (long)64 * ldb;
    int dslot = tid * 8;  // bf16 elements

#define STAGE_SLOT(SBASE, KK)                          \
    {                                                  \
        bf16* bufA = (bf16*)(SBASE);                   \
        bf16* bufB = bufA + 4096;                      \
        gl16(gA0 + (KK), bufA + dslot);                \
        gl16(gA1 + (KK), bufA + 2048 + dslot);         \
        gl16(gB0 + (KK), bufB + dslot);                \
        gl16(gB1 + (KK), bufB + 2048 + dslot);         \
    }

    // prologue: prefetch distance 2
    STAGE_SLOT(smem, kbeg);
    if (kbeg + 32 < kend) STAGE_SLOT(smem + 16384, kbeg + 32);

    int cur = 0;
    for (int k0 = kbeg; k0 < kend; k0 += 32) {
        __builtin_amdgcn_s_barrier();
        __builtin_amdgcn_sched_barrier(0);
        if (k0 + 64 < kend) {
            int ps = (cur == 0) ? 2 : cur - 1;  // (cur+2)%3
            STAGE_SLOT(smem + ps * 16384, k0 + 64);
        }
        int rem = (kend - k0 - 32) >> 5;
        if (rem >= 2)      asm volatile("s_waitcnt vmcnt(8)" ::: "memory");
        else if (rem == 1) asm volatile("s_waitcnt vmcnt(4)" ::: "memory");
        else               asm volatile("s_waitcnt vmcnt(0)" ::: "memory");
        __builtin_amdgcn_s_barrier();
        __builtin_amdgcn_sched_barrier(0);
        bf16* cbA = (bf16*)(smem + cur * 16384);
        bf16* cbB = cbA + 4096;
        short8 af[4], bfr[4];
#pragma unroll
        for (int i = 0; i < 4; i++) {
            int row = wm + i * 16 + lm;
            af[i] = *(const short8*)(cbA + row * 32 + ((((row >> 1) & 3) ^ kh) << 3));
        }
#pragma unroll
        for (int j = 0; j < 4; j++) {
            int row = wn + j * 16 + lm;
            bfr[j] = *(const short8*)(cbB + row * 32 + ((((row >> 1) & 3) ^ kh) << 3));
        }
#pragma unroll
        for (int i = 0; i < 4; i++)
#pragma unroll
            for (int j = 0; j < 4; j++)
                acc[i][j] = __builtin_amdgcn_mfma_f32_16x16x32_bf16(af[i], bfr[j], acc[i][j], 0, 0, 0);
        cur = (cur == 2) ? 0 : cur + 1;
    }
#undef STAGE_SLOT

    if (EPI == EPI_NONE_F32) {
        long cbase = (long)z * sC;
#pragma unroll
        for (int i = 0; i < 4; i++)
#pragma unroll
            for (int j = 0; j < 4; j++)
#pragma unroll
                for (int r = 0; r < 4; r++) {
                    int gm = bm + wm + i * 16 + kh * 4 + r;
                    int gn = bn + wn + j * 16 + lm;
                    ((float*)Cv)[cbase + (long)gm * ldc + gn] = acc[i][j][r];
                }
        return;
    }

    // ---- LDS-repack epilogue: two 64-row passes, coalesced 16B stores ----
    bf16* Cb = (bf16*)Cv + (long)z * sC;
#pragma unroll
    for (int p = 0; p < 2; p++) {
        __syncthreads();
        if ((w >> 1) == p) {
#pragma unroll
            for (int i = 0; i < 4; i++)
#pragma unroll
                for (int j = 0; j < 4; j++)
#pragma unroll
                    for (int r = 0; r < 4; r++) {
                        int rr = i * 16 + kh * 4 + r;
                        int cc = wn + j * 16 + lm;
                        float val = acc[i][j][r];
                        if (EPI == EPI_RELU_BF16 || EPI == EPI_RELU_MULX_BF16) val = fmaxf(val, 0.f);
                        R[rr * 136 + cc] = __float2bfloat16(val);
                    }
        }
        __syncthreads();
#pragma unroll
        for (int it = 0; it < 4; it++) {
            int row_l = it * 16 + (tid >> 4);
            int c8 = (tid & 15) * 8;
            short8 vv = *(const short8*)(R + row_l * 136 + c8);
            int gm = bm + p * 64 + row_l;
            long off = (long)gm * ldc + bn + c8;
            if (EPI == EPI_NONE_BF16) {
                *(short8*)(Cb + off) = vv;
            } else if (EPI == EPI_MASK_BF16) {
                short8 oo;
#pragma unroll
                for (int k = 0; k < 8; k++) {
                    int s = bn + c8 + k;
                    float f = bfu2f(vv[k]);
                    f = (s < gm) ? f * exp2f((float)(gm - s) * LOG2_DECAY) : 0.f;
                    oo[k] = f2bfu(f);
                }
                *(short8*)(Cb + off) = oo;
            } else if (EPI == EPI_RELU_BF16) {
                *(short8*)(Cb + off) = vv;
                float s = 0.f;
#pragma unroll
                for (int k = 0; k < 8; k++) s += bfu2f(vv[k]);
#pragma unroll
                for (int o = 8; o > 0; o >>= 1) s += __shfl_down(s, o, 16);
                if ((tid & 15) == 0) atomicAdd(&Wsum[gm], s);
            } else {  // EPI_RELU_MULX_BF16
                short8 xx = *(const short8*)(Xaux + off);
                short8 oo;
#pragma unroll
                for (int k = 0; k < 8; k++) {
                    float prod = bfu2f(vv[k]) * fmaxf(bfu2f(xx[k]), 0.f);
                    oo[k] = f2bfu(prod);
                }
                *(short8*)(Cb + off) = oo;
            }
        }
    }
}

// ---------------- Z GEMM v2: BM=64, BN=256(full) -> Xb read ONCE; split-K 4 ----------------
// 256 threads (4 waves, wave-tile 64x64), 40KB LDS double-buffer -> grid (128,4)
// = 512 blocks = 2 blocks/CU (fixes R9's 1/CU occupancy trap). Counted vmcnt(5),
// 0-conflict chunk-XOR swizzle, coalesced bf16 repack epilogue into Gp region.
__global__ __launch_bounds__(256) void k_zgemm64(const bf16* __restrict__ A,   // M x NN (Xb)
                                                 const bf16* __restrict__ B,   // DD x NN (Eb)
                                                 bf16* __restrict__ Zp) {      // 4 x M x DD bf16
    __shared__ __align__(16) char smem[40960];  // 2 x (As 4KB | Bs 16KB)
    bf16* R = (bf16*)smem;                      // [64][264] repack overlay (33.8KB)

    int bx = blockIdx.x;             // 128 M-blocks
    bx = (bx & 7) * 16 + (bx >> 3);  // bijective XCD swizzle (128 % 8 == 0)
    int ks = blockIdx.y;             // 4 K-splits
    int bm = bx * 64;
    int kbeg = ks * 1024, kend = kbeg + 1024;

    int tid = threadIdx.x, wid = tid >> 6, lane = tid & 63;
    int wn = wid * 64;               // wave grid 1(M) x 4(N); wave tile 64x64
    int lm = lane & 15, kh = lane >> 4;

    int srow = tid >> 2;             // 0..63
    int swzcol = (((tid & 3) ^ ((srow >> 1) & 3)) << 3);
    const bf16* gA  = A + (long)(bm + srow) * NN + swzcol;
    const bf16* gB0 = B + (long)srow * NN + swzcol;   // Eb rows 0-63 (+64g via offsets)
    int chunk = ((kh ^ ((lm >> 1) & 3)) << 3);

    floatx4 acc[4][4];
#pragma unroll
    for (int i = 0; i < 4; i++)
#pragma unroll
        for (int j = 0; j < 4; j++) acc[i][j] = (floatx4){0.f, 0.f, 0.f, 0.f};

#define STAGEZ(SBASE, KK)                                        \
    {                                                            \
        bf16* As_ = (bf16*)(SBASE);                              \
        bf16* Bs_ = As_ + 2048;                                  \
        gl16(gA + (KK), As_ + tid * 8);                          \
        gl16(gB0 + (KK), Bs_ + tid * 8);                         \
        gl16(gB0 + (long)64 * NN + (KK), Bs_ + 2048 + tid * 8);  \
        gl16(gB0 + (long)128 * NN + (KK), Bs_ + 4096 + tid * 8); \
        gl16(gB0 + (long)192 * NN + (KK), Bs_ + 6144 + tid * 8); \
    }

    STAGEZ(smem, kbeg);  // prologue

    int cur = 0;
    for (int k0 = kbeg; k0 < kend; k0 += 32) {
        __builtin_amdgcn_s_barrier();
        __builtin_amdgcn_sched_barrier(0);
        bool has = (k0 + 32) < kend;
        if (has) STAGEZ(smem + ((cur ^ 1) * 20480), k0 + 32);
        if (has) asm volatile("s_waitcnt vmcnt(5)" ::: "memory");
        else     asm volatile("s_waitcnt vmcnt(0)" ::: "memory");
        __builtin_amdgcn_s_barrier();
        __builtin_amdgcn_sched_barrier(0);
        bf16* cbA = (bf16*)(smem + cur * 20480);
        bf16* cbB = cbA + 2048;
        short8 af[4], bfr[4];
#pragma unroll
        for (int i = 0; i < 4; i++)
            af[i] = *(const short8*)(cbA + (i * 16 + lm) * 32 + chunk);
#pragma unroll
        for (int j = 0; j < 4; j++)
            bfr[j] = *(const short8*)(cbB + (wn + j * 16 + lm) * 32 + chunk);
#pragma unroll
        for (int i = 0; i < 4; i++)
#pragma unroll
            for (int j = 0; j < 4; j++)
                acc[i][j] = __builtin_amdgcn_mfma_f32_16x16x32_bf16(af[i], bfr[j], acc[i][j], 0, 0, 0);
        cur ^= 1;
    }
#undef STAGEZ

    // ---- repack epilogue: single pass (every wave owns a 64-col slice of all 64 rows) ----
    bf16* Cb = Zp + (long)ks * 8192 * DD;
    __syncthreads();
#pragma unroll
    for (int i = 0; i < 4; i++)
#pragma unroll
        for (int j = 0; j < 4; j++)
#pragma unroll
            for (int r = 0; r < 4; r++) {
                int rr = i * 16 + kh * 4 + r;
                int cc = wn + j * 16 + lm;
                R[rr * 264 + cc] = __float2bfloat16(acc[i][j][r]);
            }
    __syncthreads();
#pragma unroll
    for (int it = 0; it < 8; it++) {
        int row_l = it * 8 + (tid >> 5);
        int c8 = (tid & 31) * 8;
        short8 vv = *(const short8*)(R + row_l * 264 + c8);
        *(short8*)(Cb + (long)(bm + row_l) * DD + c8) = vv;
    }
}

// ---------------- a* GEMM: A = sum of 4 masked bf16 score partials (reg-staged), B = Ut ----------------
__global__ __launch_bounds__(256) void k_astar(const bf16* __restrict__ Gp,
                                               const bf16* __restrict__ Ut,
                                               bf16* __restrict__ Ap) {
    __shared__ __align__(16) char smem[32768];
    bf16* R = (bf16*)smem;

    int b = blockIdx.z;
    int y = blockIdx.y;
    int by = (y >= 1) ? 1 : 0, ks = (y == 2) ? 1 : 0;
    int bx = blockIdx.x;
    int bm = by * 128, bn = bx * 128, kbeg = ks * 128;
    int tid = threadIdx.x;
    int srow = tid >> 2;
    int scol = ((((srow >> 1) & 3) ^ (tid & 3)) << 3);
    int w = tid >> 6, lane = tid & 63;
    int wm = (w >> 1) * 64, wn = (w & 1) * 64;
    int lm = lane & 15, kh = lane >> 4;

    const bf16* gA = Gp + (long)b * 4 * 65536;
    long aoff0 = (long)(bm + srow) * TT + scol + kbeg;
    long aoff1 = (long)(bm + srow + 64) * TT + scol + kbeg;
    const bf16* gB0 = Ut + (long)b * DD * TT + (long)(bn + srow) * TT + scol + kbeg;
    const bf16* gB1 = gB0 + (long)64 * TT;
    int dslot = tid * 8;

    floatx4 acc[4][4];
#pragma unroll
    for (int i = 0; i < 4; i++)
#pragma unroll
        for (int j = 0; j < 4; j++) acc[i][j] = (floatx4){0.f, 0.f, 0.f, 0.f};

#define LOAD4SUM(DST, AOFF)                                        \
    {                                                              \
        short8 p0 = *(const short8*)(gA + (AOFF));                 \
        short8 p1 = *(const short8*)(gA + 65536 + (AOFF));         \
        short8 p2 = *(const short8*)(gA + 2 * 65536 + (AOFF));     \
        short8 p3 = *(const short8*)(gA + 3 * 65536 + (AOFF));     \
        short8 o_;                                                 \
        _Pragma("unroll")                                          \
        for (int k_ = 0; k_ < 8; k_++)                             \
            o_[k_] = f2bfu(bfu2f(p0[k_]) + bfu2f(p1[k_]) +         \
                           bfu2f(p2[k_]) + bfu2f(p3[k_]));         \
        DST = o_;                                                  \
    }

    {
        bf16* As_ = (bf16*)smem;
        bf16* Bs_ = As_ + 4096;
        gl16(gB0, Bs_ + dslot);
        gl16(gB1, Bs_ + 2048 + dslot);
        short8 ra0, ra1;
        LOAD4SUM(ra0, aoff0);
        LOAD4SUM(ra1, aoff1);
        *(short8*)(As_ + dslot) = ra0;
        *(short8*)(As_ + 2048 + dslot) = ra1;
    }
    __syncthreads();

    int cur = 0;
    for (int kk = 0; kk < 128; kk += 32) {
        bf16* cbA = (bf16*)(smem + cur * 16384);
        bf16* cbB = cbA + 4096;
        bf16* nbA = (bf16*)(smem + (cur ^ 1) * 16384);
        bf16* nbB = nbA + 4096;
        short8 na0, na1;
        bool has = (kk + 32) < 128;
        if (has) {
            gl16(gB0 + kk + 32, nbB + dslot);
            gl16(gB1 + kk + 32, nbB + 2048 + dslot);
            LOAD4SUM(na0, aoff0 + kk + 32);
            LOAD4SUM(na1, aoff1 + kk + 32);
        }
        short8 af[4], bfr[4];
#pragma unroll
        for (int i = 0; i < 4; i++) {
            int row = wm + i * 16 + lm;
            af[i] = *(const short8*)(cbA + row * 32 + ((((row >> 1) & 3) ^ kh) << 3));
        }
#pragma unroll
        for (int j = 0; j < 4; j++) {
            int row = wn + j * 16 + lm;
            bfr[j] = *(const short8*)(cbB + row * 32 + ((((row >> 1) & 3) ^ kh) << 3));
        }
#pragma unroll
        for (int i = 0; i < 4; i++)
#pragma unroll
            for (int j = 0; j < 4; j++)
                acc[i][j] = __builtin_amdgcn_mfma_f32_16x16x32_bf16(af[i], bfr[j], acc[i][j], 0, 0, 0);
        if (has) {
            *(short8*)(nbA + dslot) = na0;
            *(short8*)(nbA + 2048 + dslot) = na1;
        }
        __syncthreads();
        cur ^= 1;
    }
#undef LOAD4SUM

    bf16* Cb = Ap + ((long)b * 2 + ks) * 65536;
#pragma unroll
    for (int p = 0; p < 2; p++) {
        __syncthreads();
        if ((w >> 1) == p) {
#pragma unroll
            for (int i = 0; i < 4; i++)
#pragma unroll
                for (int j = 0; j < 4; j++)
#pragma unroll
                    for (int r = 0; r < 4; r++) {
                        int rr = i * 16 + kh * 4 + r;
                        int cc = wn + j * 16 + lm;
                        R[rr * 136 + cc] = __float2bfloat16(acc[i][j][r]);
                    }
        }
        __syncthreads();
#pragma unroll
        for (int it = 0; it < 4; it++) {
            int row_l = it * 16 + (tid >> 4);
            int c8 = (tid & 15) * 8;
            short8 vv = *(const short8*)(R + row_l * 136 + c8);
            int gm = bm + p * 64 + row_l;
            *(short8*)(Cb + (long)gm * DD + bn + c8) = vv;
        }
    }
}

// ---------------- scalar normalizer recurrence ----------------
__global__ __launch_bounds__(256) void k_scalar_scan(const float* __restrict__ Wsum,
                                                     float* __restrict__ invS) {
    __shared__ float sw[BB * TT];
    for (int i = threadIdx.x; i < BB * TT; i += 256) sw[i] = Wsum[i];
    __syncthreads();
    int b = threadIdx.x;
    if (b < BB) {
        float sig = 0.f;
        for (int t = 0; t < TT; t++) {
            float S = DECAY * sig + sw[b * TT + t];
            float inv = 1.f / (S + EPS);
            invS[b * TT + t] = inv;
            sig = S * inv;
        }
    }
}

// ---------------- barrier-free column scan: x = (0.97 x + w) * invS[t] ----------------
__global__ __launch_bounds__(256) void k_colscan(bf16* __restrict__ W,
                                                 const float* __restrict__ invS) {
    __shared__ float sv[TT];
    int b = blockIdx.y;
    sv[threadIdx.x] = invS[b * TT + threadIdx.x];
    __syncthreads();
    int n = blockIdx.x * 256 + threadIdx.x;
    bf16* p = W + (long)b * TT * NN + n;
    float x = 0.f;
    for (int t = 0; t < TT; t++) {
        float w = __bfloat162float(p[(long)t * NN]);
        x = (DECAY * x + w) * sv[t];
        p[(long)t * NN] = __float2bfloat16(x);
    }
}

// ---------------- sum a* partials (1 or 2) + row layernorm -> ALN bf16 ----------------
__global__ __launch_bounds__(256) void k_ln_rows(const bf16* __restrict__ Ap,
                                                 bf16* __restrict__ O) {
    __shared__ float s4[4];
    long r = blockIdx.x;
    int d = threadIdx.x;
    long b = r >> 8, t = r & 255;
    long base = (b * 2) * 65536 + t * 256 + d;
    float z = bfu2f(*(const short*)&Ap[base]);
    if (t >= 128) z += bfu2f(*(const short*)&Ap[base + 65536]);
    float m = blk_sum_256(z, s4) * (1.0f / DD);
    float zc = z - m;
    float var = blk_sum_256(zc * zc, s4) * (1.0f / (DD - 1));
    O[r * DD + d] = __float2bfloat16(zc / (sqrtf(fmaxf(var, 0.f)) + EPS));
}

// ---------------- sum 4 bf16 Z partials + layernorm -> output ----------------
__global__ __launch_bounds__(256) void k_final_ln(const bf16* __restrict__ Zp,
                                                  void* __restrict__ out,
                                                  const int* __restrict__ flag) {
    __shared__ float s4[4];
    long r = blockIdx.x;
    int d = threadIdx.x;
    const long SL = (long)8192 * 256;
    long o = r * DD + d;
    float z = bfu2f(*(const short*)&Zp[o]) + bfu2f(*(const short*)&Zp[o + SL]) +
              bfu2f(*(const short*)&Zp[o + 2 * SL]) + bfu2f(*(const short*)&Zp[o + 3 * SL]);
    float m = blk_sum_256(z, s4) * (1.0f / DD);
    float zc = z - m;
    float var = blk_sum_256(zc * zc, s4) * (1.0f / (DD - 1));
    float v = zc / (sqrtf(fmaxf(var, 0.f)) + EPS);
    if (flag[0]) ((bf16*)out)[o] = __float2bfloat16(v);
    else ((float*)out)[o] = v;
}

extern "C" void kernel_launch(void* const* d_in, const int* in_sizes, int n_in,
                              void* d_out, int out_size, void* d_ws, size_t ws_size,
                              hipStream_t stream) {
    const int* idx = (const int*)d_in[0];
    const void* emb = d_in[1];
    const void* E = d_in[2];
    const void* Dx = d_in[3];
    const void* Dy = d_in[4];

    // ---- workspace carve (bytes) ----
    char* base = (char*)d_ws;
    size_t off = 0;
    int* flag = (int*)base; off += 1024;
    bf16* Dxb = (bf16*)(base + off); off += (size_t)NN * DD * 2;
    bf16* Dyb = (bf16*)(base + off); off += (size_t)NN * DD * 2;
    bf16* Eb  = (bf16*)(base + off); off += (size_t)DD * NN * 2;
    bf16* Vpb = (bf16*)(base + off); off += (size_t)BB * TT * DD * 2;
    bf16* Ub  = (bf16*)(base + off); off += (size_t)BB * TT * DD * 2;
    bf16* Ut  = (bf16*)(base + off); off += (size_t)BB * TT * DD * 2;
    float* Wsum = (float*)(base + off); off += (size_t)BB * TT * 4;
    float* invS = (float*)(base + off); off += (size_t)BB * TT * 4;
    bf16* ALNb = (bf16*)(base + off); off += (size_t)BB * TT * DD * 2;
    bf16* Gp = (bf16*)(base + off); off += (size_t)4 * BB * TT * TT * 2;  // 16.8MB masked bf16 partials
    bf16* Ap = (bf16*)(base + off); off += (size_t)2 * BB * TT * DD * 2;  // 8.4MB a* bf16 partials
    bf16* Zp = Gp;  // Z bf16 partials (4 x 8192 x 256 = 16.8MB) alias Gp (dead after k_astar)
    bf16* Xb = (bf16*)(base + off); off += (size_t)BB * TT * NN * 2;      // 67MB

    const int M = BB * TT;  // 8192

    k_detect<<<1, 256, 0, stream>>>((const unsigned short*)emb, flag);
    k_convert3<<<3 * NN * DD / 8 / 256, 256, 0, stream>>>(Dx, Dy, E, Dxb, Dyb, Eb, flag);
    k_gather_ln<<<M, 256, 0, stream>>>(emb, idx, Vpb, Ub, flag);
    k_transpose<<<dim3(8, 8, BB), 256, 0, stream>>>(Ub, Ut);

    hipMemsetAsync(Wsum, 0, (size_t)M * 4, stream);

    // W = relu(Vp @ Dx^T) -> Xb (bf16), rowsums fused via atomics
    k_fused256<EPI_RELU_BF16><<<dim3(16, 32), 512, 0, stream>>>(Vpb, Dxb, Xb, nullptr, Wsum);

    k_scalar_scan<<<1, 256, 0, stream>>>(Wsum, invS);
    k_colscan<<<dim3(16, BB, 1), 256, 0, stream>>>(Xb, invS);

    // scores partials: 3 lower-triangular tiles, split-K 4, MASKED bf16 partials
    k_mfma_nt<EPI_MASK_BF16, 4, 1, 0><<<dim3(3, 1, BB * 4), 256, 0, stream>>>(
        NN, Xb, NN, (long)TT * NN, Xb, NN, (long)TT * NN, Gp, TT, (long)TT * TT, nullptr, nullptr);

    // a* = (sum of masked partials) @ U
    k_astar<<<dim3(2, 3, BB), 256, 0, stream>>>(Gp, Ut, Ap);
    k_ln_rows<<<M, 256, 0, stream>>>(Ap, ALNb);

    // Y = relu(ALN @ Dy^T) * relu(X), in place over Xb
    k_fused256<EPI_RELU_MULX_BF16><<<dim3(16, 32), 512, 0, stream>>>(ALNb, Dyb, Xb, Xb, nullptr);

    // Z partials = Y @ E^T : BM=64, BN=256 (Xb read once), split-K 4, 2 blocks/CU
    k_zgemm64<<<dim3(128, 4), 256, 0, stream>>>(Xb, Eb, Zp);

    k_final_ln<<<M, 256, 0, stream>>>(Zp, d_out, flag);
}